// Round 7
// baseline (1870.004 us; speedup 1.0000x reference)
//
#include <hip/hip_runtime.h>
#include <hip/hip_bf16.h>

// DGCNN_Seg forward. B=2, N=4096, K=20. fp32 in/out; bf16 MFMA for layer-4 +
// head GEMMs; fp32 for kNN-feeding path.
// Round 7: fused k_knn (dist GEMM + online top-20, one dispatch per layer)
// replaces k_dist+k_topk; tiny k_kmerge merges 4 j-split partials.

#define DEVI static __device__ __forceinline__
typedef __attribute__((ext_vector_type(8))) short bf16x8;   // 8 bf16 = 4 VGPR
typedef __attribute__((ext_vector_type(4))) float f32x4;    // MFMA acc
typedef unsigned long long ull;
#define JS 4  // j-splits per batch in k_knn

DEVI float lrelu(float y) { return y > 0.f ? y : 0.2f * y; }
DEVI unsigned okey(float f) {
  unsigned u = __float_as_uint(f);
  return (f < 0.f) ? ~u : (u | 0x80000000u);
}
DEVI float dekey(unsigned k) {
  return __uint_as_float((k & 0x80000000u) ? (k & 0x7fffffffu) : ~k);
}

// ---------------- weight fp32 -> bf16 pack ----------------
__global__ __launch_bounds__(64) void k_conv(const float* __restrict__ src, int lds, int off,
                                             int sub, int Kc, __hip_bfloat16* __restrict__ dst) {
  int o = blockIdx.x, c = blockIdx.y * 64 + threadIdx.x;
  float v = src[(size_t)o * lds + off + c];
  if (sub) v -= src[(size_t)o * lds + c];
  dst[(size_t)o * Kc + c] = __float2bfloat16(v);
}

// ---------------- row squared-norms: one wave per row ----------------
__global__ __launch_bounds__(256) void k_xx(const float* __restrict__ F, int ldf, int C,
                                            float* __restrict__ xx) {
  int lane = threadIdx.x & 63;
  int row = blockIdx.x * 4 + (threadIdx.x >> 6);
  const float* f = F + (size_t)row * ldf;
  float s = 0.f;
  for (int c = lane; c < C; c += 64) { float v = f[c]; s += v * v; }
#pragma unroll
  for (int off = 32; off; off >>= 1) s += __shfl_xor(s, off, 64);
  if (lane == 0) xx[row] = s;
}

// ---------------- FUSED kNN: dist GEMM tile + online top-20 ----------------
// grid (64 i-tiles, JS j-splits, 2 batches), block 256.
// Per j-tile: fp32 GEMM (identical fmaf order to old k_dist -> bit-identical
// distances) -> D-tile in LDS -> 256 threads = 64 rows x 4 quarters scan into
// per-thread sorted top-20 (u64 key = okey(d)<<32 | j). End: spill + 4-way
// merge per row -> sorted partial per (row, j-split).
__global__ __launch_bounds__(256) void k_knn(const float* __restrict__ F, int ldf, int C,
                                             const float* __restrict__ xx,
                                             ull* __restrict__ part) {
  __shared__ __align__(16) char smem[43008];
  float (*As)[68] = (float(*)[68])smem;              // 16x68x4 = 4352 B
  float (*Bs)[68] = (float(*)[68])(smem + 4352);     // 4352 B
  float (*Dt)[66] = (float(*)[66])(smem + 8704);     // 64x66x4 = 16896 B
  ull* spill = (ull*)smem;                           // 256x21x8 = 43008 B (post-loop)
  const int tid = threadIdx.x;
  const int tx = tid & 15, ty = tid >> 4;
  const int b = blockIdx.z;
  const int i0 = blockIdx.x * 64;
  const int jbase = blockIdx.y * (4096 / JS);
  const float* Fb = F + (size_t)b * 4096 * ldf;
  const float* xxb = xx + b * 4096;
  const int row = tid >> 2, q4 = (tid & 3) * 4;
  const int srow = tid & 63, sq = tid >> 6;  // scan mapping: row, quarter
  ull arr[20];
#pragma unroll
  for (int t = 0; t < 20; ++t) arr[t] = ~0ull;
  float xi[4];
#pragma unroll
  for (int ii = 0; ii < 4; ++ii) xi[ii] = xxb[i0 + ty * 4 + ii];

  for (int jt = 0; jt < 4096 / JS / 64; ++jt) {
    const int j0 = jbase + jt * 64;
    float acc[4][4] = {};
    for (int c0 = 0; c0 < C; c0 += 16) {
      if (C - c0 >= 16) {
        float4 a = *(const float4*)(Fb + (size_t)(i0 + row) * ldf + c0 + q4);
        float4 w = *(const float4*)(Fb + (size_t)(j0 + row) * ldf + c0 + q4);
        As[q4 + 0][row] = a.x; As[q4 + 1][row] = a.y; As[q4 + 2][row] = a.z; As[q4 + 3][row] = a.w;
        Bs[q4 + 0][row] = w.x; Bs[q4 + 1][row] = w.y; Bs[q4 + 2][row] = w.z; Bs[q4 + 3][row] = w.w;
      } else {
#pragma unroll
        for (int e = 0; e < 4; ++e) {
          int c = c0 + q4 + e;
          As[q4 + e][row] = (c < C) ? Fb[(size_t)(i0 + row) * ldf + c] : 0.f;
          Bs[q4 + e][row] = (c < C) ? Fb[(size_t)(j0 + row) * ldf + c] : 0.f;
        }
      }
      __syncthreads();
#pragma unroll
      for (int kk = 0; kk < 16; ++kk) {
        const float4 a4 = *(const float4*)&As[kk][ty * 4];
        const float4 b4 = *(const float4*)&Bs[kk][tx * 4];
        const float av[4] = {a4.x, a4.y, a4.z, a4.w};
        const float bv[4] = {b4.x, b4.y, b4.z, b4.w};
#pragma unroll
        for (int ii = 0; ii < 4; ++ii)
#pragma unroll
          for (int jj = 0; jj < 4; ++jj)
            acc[ii][jj] = fmaf(av[ii], bv[jj], acc[ii][jj]);
      }
      __syncthreads();
    }
    // D tile -> LDS (same formula/order as old k_dist)
#pragma unroll
    for (int ii = 0; ii < 4; ++ii)
#pragma unroll
      for (int jj = 0; jj < 4; ++jj)
        Dt[ty * 4 + ii][tx * 4 + jj] = xi[ii] + xxb[j0 + tx * 4 + jj] - 2.f * acc[ii][jj];
    __syncthreads();
    // scan 16 candidates into per-thread sorted top-20
#pragma unroll
    for (int k = 0; k < 16; ++k) {
      int jl = sq * 16 + k;
      float d = Dt[srow][jl];
      ull key = ((ull)okey(d) << 32) | (unsigned)(j0 + jl);
      if (key < arr[19]) {
#pragma unroll
        for (int t2 = 19; t2 > 0; --t2) {
          bool sh = key < arr[t2 - 1];
          ull c2 = sh ? arr[t2 - 1] : key;
          arr[t2] = (c2 < arr[t2]) ? c2 : arr[t2];
        }
        arr[0] = (key < arr[0]) ? key : arr[0];
      }
    }
    __syncthreads();
  }
  // spill lists (stride 21 u64 -> 2-way banks, free)
#pragma unroll
  for (int t = 0; t < 20; ++t) spill[(size_t)tid * 21 + t] = arr[t];
  __syncthreads();
  if (tid < 64) {
    const int r = tid;
    int p0 = 0, p1 = 0, p2 = 0, p3 = 0;
    ull* op = part + (((size_t)b * 4096 + i0 + r) * JS + blockIdx.y) * 20;
    for (int o = 0; o < 20; ++o) {
      ull v0 = spill[(size_t)(r) * 21 + p0];
      ull v1 = spill[(size_t)(64 + r) * 21 + p1];
      ull v2 = spill[(size_t)(128 + r) * 21 + p2];
      ull v3 = spill[(size_t)(192 + r) * 21 + p3];
      ull m01 = v0 < v1 ? v0 : v1;
      ull m23 = v2 < v3 ? v2 : v3;
      ull best = m01 < m23 ? m01 : m23;
      if (best == v0) ++p0; else if (best == v1) ++p1;
      else if (best == v2) ++p2; else ++p3;
      op[o] = best;
    }
  }
}

// ---------------- merge JS sorted partials per row -> final indices ----------------
__global__ __launch_bounds__(256) void k_kmerge(const ull* __restrict__ part,
                                                int* __restrict__ idx) {
  const int rowg = blockIdx.x * 256 + threadIdx.x;  // 0..8191
  const ull* pr = part + (size_t)rowg * JS * 20;
  int p[JS] = {};
  int* op = idx + (size_t)rowg * 20;
  for (int o = 0; o < 20; ++o) {
    ull best = ~0ull;
    int bq = 0;
#pragma unroll
    for (int q = 0; q < JS; ++q) {
      ull v = pr[q * 20 + p[q]];
      if (v < best) { best = v; bq = q; }
    }
    ++p[bq];
    op[o] = (int)(best & 0xffffffffull);
  }
}

// ---------------- EdgeConv layer 1 (fp32, Cin=3): one wave per point ----------------
__global__ __launch_bounds__(256) void k_edge1(const float* __restrict__ xf,
                                               const float* __restrict__ W1,
                                               const float* __restrict__ s1,
                                               const float* __restrict__ b1,
                                               const int* __restrict__ idx,
                                               float* __restrict__ xcat,
                                               __hip_bfloat16* __restrict__ xcatb) {
  const int lane = threadIdx.x & 63;
  const int p = blockIdx.x * 4 + (threadIdx.x >> 6);
  const int bb = p >> 12;
  float wl[3], wr[3];
#pragma unroll
  for (int c = 0; c < 3; ++c) {
    wl[c] = W1[lane * 6 + c];
    wr[c] = W1[lane * 6 + 3 + c];
  }
  const float s = s1[lane], bi = b1[lane];
  const float* xc = xf + (size_t)p * 3;
  const float x0 = xc[0], x1 = xc[1], x2 = xc[2];
  const float t = x0 * (wr[0] - wl[0]) + x1 * (wr[1] - wl[1]) + x2 * (wr[2] - wl[2]);
  const int* ir = idx + (size_t)p * 20;
  float best = -INFINITY;
  for (int k = 0; k < 20; ++k) {
    int j = ir[k];
    const float* xn = xf + ((size_t)(bb << 12) + j) * 3;
    float y = t + xn[0] * wl[0] + xn[1] * wl[1] + xn[2] * wl[2];
    y = lrelu(y * s + bi);
    best = fmaxf(best, y);
  }
  xcat[(size_t)p * 512 + lane] = best;
  xcatb[(size_t)p * 512 + lane] = __float2bfloat16(best);
}

// ---------------- fp32 pointwise GEMM, raw store (T for layers 2-3) ----------------
__global__ __launch_bounds__(256) void k_pwT(const float* __restrict__ A, int lda, int K,
                                             const float* __restrict__ W, int ldw, int wsub,
                                             float* __restrict__ out, int ldo) {
  __shared__ __align__(16) float As[16][68];
  __shared__ __align__(16) float Bs[16][68];
  const int tid = threadIdx.x;
  const int tx = tid & 15, ty = tid >> 4;
  const int i0 = blockIdx.x * 64, o0 = blockIdx.y * 64;
  const int row = tid >> 2, q = (tid & 3) * 4;
  float acc[4][4] = {};
  for (int c0 = 0; c0 < K; c0 += 16) {
    float4 a = *(const float4*)(A + (size_t)(i0 + row) * lda + c0 + q);
    As[q + 0][row] = a.x; As[q + 1][row] = a.y; As[q + 2][row] = a.z; As[q + 3][row] = a.w;
    const float* wp = W + (size_t)(o0 + row) * ldw + c0 + q;
#pragma unroll
    for (int e = 0; e < 4; ++e) Bs[q + e][row] = wp[wsub + e] - wp[e];
    __syncthreads();
#pragma unroll
    for (int kk = 0; kk < 16; ++kk) {
      const float4 a4 = *(const float4*)&As[kk][ty * 4];
      const float4 b4 = *(const float4*)&Bs[kk][tx * 4];
      const float av[4] = {a4.x, a4.y, a4.z, a4.w};
      const float bv[4] = {b4.x, b4.y, b4.z, b4.w};
#pragma unroll
      for (int ii = 0; ii < 4; ++ii)
#pragma unroll
        for (int jj = 0; jj < 4; ++jj)
          acc[ii][jj] = fmaf(av[ii], bv[jj], acc[ii][jj]);
    }
    __syncthreads();
  }
#pragma unroll
  for (int ii = 0; ii < 4; ++ii)
#pragma unroll
    for (int jj = 0; jj < 4; ++jj)
      out[(size_t)(i0 + ty * 4 + ii) * ldo + o0 + tx * 4 + jj] = acc[ii][jj];
}

// ---------------- fp32 EdgeConv GEMM (layers 2-3; feeds kNN, stays exact) ----------------
__global__ __launch_bounds__(256) void k_edge(const float* __restrict__ F, int ldf, int Cin,
                                              const float* __restrict__ W,
                                              const float* __restrict__ sc,
                                              const float* __restrict__ bi,
                                              const int* __restrict__ idx,
                                              const float* __restrict__ T, int ldt,
                                              float* __restrict__ out,
                                              __hip_bfloat16* __restrict__ outb) {
  __shared__ float As[16][81];
  __shared__ __align__(16) float Bs[16][68];
  __shared__ float Ys[80][65];
  const int tid = threadIdx.x;
  const int tx = tid & 15, ty = tid >> 4;
  const int r0 = blockIdx.x * 80;
  const int o0 = blockIdx.y * 64;
  const int ldw = 2 * Cin;
  int grow[5], gcol[5];
#pragma unroll
  for (int l = 0; l < 5; ++l) {
    int e = tid + l * 256;
    int rr = e >> 4;
    gcol[l] = e & 15;
    int gr = r0 + rr;
    int p = gr / 20;
    int j = idx[(size_t)p * 20 + (gr % 20)];
    grow[l] = ((p >> 12) << 12) + j;
  }
  float acc[5][4] = {};
  const int wrow = tid >> 2, wq = (tid & 3) * 4;
  for (int c0 = 0; c0 < Cin; c0 += 16) {
#pragma unroll
    for (int l = 0; l < 5; ++l) {
      int e = tid + l * 256;
      As[gcol[l]][e >> 4] = F[(size_t)grow[l] * ldf + c0 + gcol[l]];
    }
    {
      const float* wp = W + (size_t)(o0 + wrow) * ldw + c0 + wq;
#pragma unroll
      for (int e = 0; e < 4; ++e) Bs[wq + e][wrow] = wp[e];
    }
    __syncthreads();
#pragma unroll
    for (int kk = 0; kk < 16; ++kk) {
      float a[5];
#pragma unroll
      for (int l = 0; l < 5; ++l) a[l] = As[kk][ty + l * 16];
      const float4 b4 = *(const float4*)&Bs[kk][tx * 4];
      const float bv[4] = {b4.x, b4.y, b4.z, b4.w};
#pragma unroll
      for (int l = 0; l < 5; ++l)
#pragma unroll
        for (int jj = 0; jj < 4; ++jj)
          acc[l][jj] = fmaf(a[l], bv[jj], acc[l][jj]);
    }
    __syncthreads();
  }
#pragma unroll
  for (int l = 0; l < 5; ++l) {
    int r = ty + l * 16;
    int p = (r0 + r) / 20;
#pragma unroll
    for (int jj = 0; jj < 4; ++jj) {
      int o = o0 + tx * 4 + jj;
      float y = (acc[l][jj] + T[(size_t)p * ldt + o]) * sc[o] + bi[o];
      Ys[r][tx * 4 + jj] = lrelu(y);
    }
  }
  __syncthreads();
  const int grp = tid >> 6, col = tid & 63;
  float m = -INFINITY;
#pragma unroll
  for (int k = 0; k < 20; ++k) m = fmaxf(m, Ys[grp * 20 + k][col]);
  const int p = blockIdx.x * 4 + grp;
  out[(size_t)p * 512 + o0 + col] = m;
  outb[(size_t)p * 512 + o0 + col] = __float2bfloat16(m);
}

// ---------------- MFMA bf16 GEMM: block 128(M)x64(N), 4 waves x (32x64) ----------------
template <int EPI>
__global__ __launch_bounds__(256) void k_mm(
    const __hip_bfloat16* __restrict__ A, int lda, int K,
    const __hip_bfloat16* __restrict__ B,  // [N][K] bf16
    const float* __restrict__ sc, const float* __restrict__ bi,
    const float* __restrict__ extra, int Ncols,
    float* __restrict__ outf, int ldof,
    __hip_bfloat16* __restrict__ outb, int ldob,
    unsigned* __restrict__ gmax) {
  __shared__ __align__(16) __hip_bfloat16 Al[128 * 40];
  __shared__ __align__(16) __hip_bfloat16 Bl[64 * 40];
  __shared__ float Red[4][64];
  const int tid = threadIdx.x, lane = tid & 63, wv = tid >> 6;
  const int m0 = blockIdx.x * 128, n0 = blockIdx.y * 64;
  const int arow = tid >> 2, akc = (tid & 3) * 8;
  const int fm = lane & 15, fq = lane >> 4;
  f32x4 acc[2][4];
#pragma unroll
  for (int mt = 0; mt < 2; ++mt)
#pragma unroll
    for (int nt = 0; nt < 4; ++nt) acc[mt][nt] = (f32x4){0.f, 0.f, 0.f, 0.f};
  for (int c0 = 0; c0 < K; c0 += 32) {
#pragma unroll
    for (int l = 0; l < 2; ++l) {
      int r = arow + l * 64;
      *(float4*)&Al[r * 40 + akc] = *(const float4*)(A + (size_t)(m0 + r) * lda + c0 + akc);
    }
    *(float4*)&Bl[arow * 40 + akc] = *(const float4*)(B + (size_t)(n0 + arow) * K + c0 + akc);
    __syncthreads();
    bf16x8 af[2], bfr[4];
#pragma unroll
    for (int mt = 0; mt < 2; ++mt)
      af[mt] = *(const bf16x8*)&Al[(wv * 32 + mt * 16 + fm) * 40 + fq * 8];
#pragma unroll
    for (int nt = 0; nt < 4; ++nt)
      bfr[nt] = *(const bf16x8*)&Bl[(nt * 16 + fm) * 40 + fq * 8];
#pragma unroll
    for (int mt = 0; mt < 2; ++mt)
#pragma unroll
      for (int nt = 0; nt < 4; ++nt)
        acc[mt][nt] = __builtin_amdgcn_mfma_f32_16x16x32_bf16(af[mt], bfr[nt], acc[mt][nt], 0, 0, 0);
    __syncthreads();
  }
  const int bidx = m0 >> 12;
  if (EPI == 0) {
#pragma unroll
    for (int mt = 0; mt < 2; ++mt)
#pragma unroll
      for (int nt = 0; nt < 4; ++nt)
#pragma unroll
        for (int r = 0; r < 4; ++r)
          outf[(size_t)(m0 + wv * 32 + mt * 16 + fq * 4 + r) * ldof + n0 + nt * 16 + fm] =
              acc[mt][nt][r];
  } else if (EPI == 1) {
#pragma unroll
    for (int nt = 0; nt < 4; ++nt) {
      int col = n0 + nt * 16 + fm;
      float s = sc[col], bb = bi[col];
      float ex = extra ? extra[bidx * Ncols + col] : 0.f;
#pragma unroll
      for (int mt = 0; mt < 2; ++mt)
#pragma unroll
        for (int r = 0; r < 4; ++r) {
          float v = lrelu((acc[mt][nt][r] + ex) * s + bb);
          size_t rr = (size_t)(m0 + wv * 32 + mt * 16 + fq * 4 + r);
          if (outf) outf[rr * ldof + col] = v;
          if (outb) outb[rr * ldob + col] = __float2bfloat16(v);
        }
    }
  } else {
#pragma unroll
    for (int nt = 0; nt < 4; ++nt) {
      int col = n0 + nt * 16 + fm;
      float s = sc[col], bb = bi[col];
      float m = -INFINITY;
#pragma unroll
      for (int mt = 0; mt < 2; ++mt)
#pragma unroll
        for (int r = 0; r < 4; ++r) m = fmaxf(m, lrelu(acc[mt][nt][r] * s + bb));
      m = fmaxf(m, __shfl_xor(m, 16, 64));
      m = fmaxf(m, __shfl_xor(m, 32, 64));
      if (fq == 0) Red[wv][nt * 16 + fm] = m;
    }
    __syncthreads();
    if (tid < 64) {
      float m = fmaxf(fmaxf(Red[0][tid], Red[1][tid]), fmaxf(Red[2][tid], Red[3][tid]));
      atomicMax(&gmax[bidx * Ncols + n0 + tid], okey(m));
    }
  }
}

// ---------------- MFMA bf16 EdgeConv (layer 4): 320 edges x 64 cols / block ----------------
__global__ __launch_bounds__(256) void k_edgem(
    const __hip_bfloat16* __restrict__ F, int ldf, int coff, int K,
    const __hip_bfloat16* __restrict__ Wl,  // [N][K] bf16
    const float* __restrict__ sc, const float* __restrict__ bi,
    const float* __restrict__ T, int N,
    const int* __restrict__ idx,
    float* __restrict__ outf, __hip_bfloat16* __restrict__ outb) {
  __shared__ __align__(16) char smem[320 * 66 * 2];  // 42240 B, overlaid stage/Ys
  __hip_bfloat16* Al = (__hip_bfloat16*)smem;              // 320*40
  __hip_bfloat16* Bl = (__hip_bfloat16*)(smem + 25600);    // 64*40
  __hip_bfloat16* Ys = (__hip_bfloat16*)smem;              // 320*66 (post-loop)
  const int tid = threadIdx.x, lane = tid & 63, wv = tid >> 6;
  const int blk = blockIdx.x, n0 = blockIdx.y * 64;
  const int arow = tid >> 2, akc = (tid & 3) * 8;
  const int fm = lane & 15, fq = lane >> 4;
  const __hip_bfloat16* ap[5];
#pragma unroll
  for (int l = 0; l < 5; ++l) {
    int row = arow + l * 64;
    int e = blk * 320 + row;
    int p = e / 20;
    int j = idx[(size_t)p * 20 + (e - p * 20)];
    int src = ((p >> 12) << 12) + j;
    ap[l] = F + (size_t)src * ldf + coff + akc;
  }
  f32x4 acc[5][4];
#pragma unroll
  for (int l = 0; l < 5; ++l)
#pragma unroll
    for (int nt = 0; nt < 4; ++nt) acc[l][nt] = (f32x4){0.f, 0.f, 0.f, 0.f};
  for (int c0 = 0; c0 < K; c0 += 32) {
#pragma unroll
    for (int l = 0; l < 5; ++l)
      *(float4*)&Al[(arow + l * 64) * 40 + akc] = *(const float4*)(ap[l] + c0);
    *(float4*)&Bl[arow * 40 + akc] = *(const float4*)(Wl + (size_t)(n0 + arow) * K + c0 + akc);
    __syncthreads();
    bf16x8 af[5], bfr[4];
#pragma unroll
    for (int l = 0; l < 5; ++l)
      af[l] = *(const bf16x8*)&Al[(wv * 80 + l * 16 + fm) * 40 + fq * 8];
#pragma unroll
    for (int nt = 0; nt < 4; ++nt)
      bfr[nt] = *(const bf16x8*)&Bl[(nt * 16 + fm) * 40 + fq * 8];
#pragma unroll
    for (int l = 0; l < 5; ++l)
#pragma unroll
      for (int nt = 0; nt < 4; ++nt)
        acc[l][nt] = __builtin_amdgcn_mfma_f32_16x16x32_bf16(af[l], bfr[nt], acc[l][nt], 0, 0, 0);
    __syncthreads();
  }
#pragma unroll
  for (int l = 0; l < 5; ++l)
#pragma unroll
    for (int nt = 0; nt < 4; ++nt)
#pragma unroll
      for (int r = 0; r < 4; ++r)
        Ys[(wv * 80 + l * 16 + fq * 4 + r) * 66 + nt * 16 + fm] = __float2bfloat16(acc[l][nt][r]);
  __syncthreads();
  const int col = tid & 63;
#pragma unroll
  for (int gi = 0; gi < 4; ++gi) {
    int grp = wv + gi * 4;
    float m = -INFINITY;
#pragma unroll
    for (int k = 0; k < 20; ++k)
      m = fmaxf(m, __bfloat162float(Ys[(grp * 20 + k) * 66 + col]));
    int p = blk * 16 + grp;
    int o = n0 + col;
    float v = lrelu((m + T[(size_t)p * N + o]) * sc[o] + bi[o]);
    outf[(size_t)p * 512 + o] = v;
    outb[(size_t)p * 512 + o] = __float2bfloat16(v);
  }
}

// ---------------- bias2: one wave per (b,o) ----------------
__global__ __launch_bounds__(256) void k_bias2(const unsigned* __restrict__ gk,
                                               const float* __restrict__ Ws1,
                                               float* __restrict__ b2g) {
  const int lane = threadIdx.x & 63;
  const int wid = (blockIdx.x * 256 + threadIdx.x) >> 6;  // 0..1023
  const int b = wid >> 9, o = wid & 511;
  const float* wr = Ws1 + (size_t)o * 1536 + 512;
  const unsigned* g = gk + b * 1024;
  float acc = 0.f;
#pragma unroll
  for (int c = lane; c < 1024; c += 64) acc = fmaf(dekey(g[c]), wr[c], acc);
#pragma unroll
  for (int off = 32; off; off >>= 1) acc += __shfl_xor(acc, off, 64);
  if (lane == 0) b2g[b * 512 + o] = acc;
}

// ---------------- final head: out = H(8192x256) . Ws3^T + bs3 (fp32) ----------------
__global__ __launch_bounds__(256) void k_out(const float* __restrict__ H,
                                             const float* __restrict__ Ws3,
                                             const float* __restrict__ bs3,
                                             float* __restrict__ out) {
  __shared__ float Ws[13][256];
  const int tid = threadIdx.x;
  for (int e = tid; e < 13 * 256; e += 256) Ws[e >> 8][e & 255] = Ws3[e];
  __syncthreads();
  const int rloc = tid >> 4, o = tid & 15;
  const int row = blockIdx.x * 16 + rloc;
  if (o < 13) {
    const float* h = H + (size_t)row * 256;
    float acc = 0.f;
    for (int c = 0; c < 256; ++c) acc = fmaf(h[c], Ws[o][c], acc);
    out[(size_t)row * 13 + o] = acc + bs3[o];
  }
}

extern "C" void kernel_launch(void* const* d_in, const int* in_sizes, int n_in,
                              void* d_out, int out_size, void* d_ws, size_t ws_size,
                              hipStream_t stream) {
  const float* X   = (const float*)d_in[0];
  const float* W1  = (const float*)d_in[1];
  const float* S1  = (const float*)d_in[2];
  const float* B1  = (const float*)d_in[3];
  const float* W2  = (const float*)d_in[4];
  const float* S2  = (const float*)d_in[5];
  const float* B2  = (const float*)d_in[6];
  const float* W3  = (const float*)d_in[7];
  const float* S3  = (const float*)d_in[8];
  const float* B3  = (const float*)d_in[9];
  const float* W4  = (const float*)d_in[10];
  const float* S4  = (const float*)d_in[11];
  const float* B4  = (const float*)d_in[12];
  const float* Wg  = (const float*)d_in[13];
  const float* Sg  = (const float*)d_in[14];
  const float* Bg  = (const float*)d_in[15];
  const float* Ws1 = (const float*)d_in[16];
  const float* Ss1 = (const float*)d_in[17];
  const float* Bs1 = (const float*)d_in[18];
  const float* Ws2 = (const float*)d_in[19];
  const float* Ss2 = (const float*)d_in[20];
  const float* Bs2 = (const float*)d_in[21];
  const float* Ws3 = (const float*)d_in[22];
  const float* Bs3 = (const float*)d_in[23];

  char* ws = (char*)d_ws;
  float*           xxb   = (float*)(ws + 0);            // 32 KB
  int*             idxb  = (int*)(ws + 32768);          // 640 KB
  unsigned*        gk    = (unsigned*)(ws + 688128);    // 8 KB
  float*           b2g   = (float*)(ws + 696320);       // 4 KB
  __hip_bfloat16*  Wgb   = (__hip_bfloat16*)(ws + 1048576);  // 1 MB
  __hip_bfloat16*  Ws1b  = (__hip_bfloat16*)(ws + 2097152);  // 512 KB
  __hip_bfloat16*  Ws2b  = (__hip_bfloat16*)(ws + 2621440);  // 256 KB
  __hip_bfloat16*  Wlb4  = (__hip_bfloat16*)(ws + 2883584);  // 64 KB
  __hip_bfloat16*  Wdb4  = (__hip_bfloat16*)(ws + 2949120);  // 64 KB
  __hip_bfloat16*  xcatb = (__hip_bfloat16*)(ws + 3145728);  // 8 MB
  float*           xcat  = (float*)(ws + 11534336);          // 16 MB
  char*            region = ws + 28311552;                   // 16 MB shared
  ull*             part  = (ull*)(region);                    // kNN phase: 8192*JS*20*8 = 5.24 MB
  float*           Tbuf  = (float*)(region);                  // post-kNN per layer: T / h2
  __hip_bfloat16*  h1b   = (__hip_bfloat16*)(region + 8388608);  // head phase

  hipMemsetAsync(gk, 0, 2 * 1024 * sizeof(unsigned), stream);

  // weight bf16 packs
  k_conv<<<dim3(256, 2), dim3(64), 0, stream>>>(W4, 256, 0, 0, 128, Wlb4);
  k_conv<<<dim3(256, 2), dim3(64), 0, stream>>>(W4, 256, 128, 1, 128, Wdb4);
  k_conv<<<dim3(1024, 8), dim3(64), 0, stream>>>(Wg, 512, 0, 0, 512, Wgb);
  k_conv<<<dim3(512, 8), dim3(64), 0, stream>>>(Ws1, 1536, 0, 0, 512, Ws1b);
  k_conv<<<dim3(256, 8), dim3(64), 0, stream>>>(Ws2, 512, 0, 0, 512, Ws2b);

  // ---- Layer 1 (C=3 -> 64) ----
  k_xx<<<dim3(2048), dim3(256), 0, stream>>>(X, 3, 3, xxb);
  k_knn<<<dim3(64, JS, 2), dim3(256), 0, stream>>>(X, 3, 3, xxb, part);
  k_kmerge<<<dim3(32), dim3(256), 0, stream>>>(part, idxb);
  k_edge1<<<dim3(2048), dim3(256), 0, stream>>>(X, W1, S1, B1, idxb, xcat, xcatb);

  // ---- Layer 2 (64 -> 64), fp32 (feeds kNN) ----
  k_xx<<<dim3(2048), dim3(256), 0, stream>>>(xcat, 512, 64, xxb);
  k_knn<<<dim3(64, JS, 2), dim3(256), 0, stream>>>(xcat, 512, 64, xxb, part);
  k_kmerge<<<dim3(32), dim3(256), 0, stream>>>(part, idxb);
  k_pwT<<<dim3(128, 1), dim3(256), 0, stream>>>(xcat, 512, 64, W2, 128, 64, Tbuf, 64);
  k_edge<<<dim3(2048, 1), dim3(256), 0, stream>>>(xcat, 512, 64, W2, S2, B2,
      idxb, Tbuf, 64, xcat + 64, xcatb + 64);

  // ---- Layer 3 (64 -> 128), fp32 (feeds kNN) ----
  k_xx<<<dim3(2048), dim3(256), 0, stream>>>(xcat + 64, 512, 64, xxb);
  k_knn<<<dim3(64, JS, 2), dim3(256), 0, stream>>>(xcat + 64, 512, 64, xxb, part);
  k_kmerge<<<dim3(32), dim3(256), 0, stream>>>(part, idxb);
  k_pwT<<<dim3(128, 2), dim3(256), 0, stream>>>(xcat + 64, 512, 64, W3, 128, 64, Tbuf, 128);
  k_edge<<<dim3(2048, 2), dim3(256), 0, stream>>>(xcat + 64, 512, 64, W3, S3, B3,
      idxb, Tbuf, 128, xcat + 128, xcatb + 128);

  // ---- Layer 4 (128 -> 256), bf16 MFMA ----
  k_xx<<<dim3(2048), dim3(256), 0, stream>>>(xcat + 128, 512, 128, xxb);
  k_knn<<<dim3(64, JS, 2), dim3(256), 0, stream>>>(xcat + 128, 512, 128, xxb, part);
  k_kmerge<<<dim3(32), dim3(256), 0, stream>>>(part, idxb);
  k_mm<0><<<dim3(64, 4), dim3(256), 0, stream>>>(xcatb + 128, 512, 128, Wdb4,
      nullptr, nullptr, nullptr, 256, Tbuf, 256, nullptr, 0, nullptr);
  k_edgem<<<dim3(512, 4), dim3(256), 0, stream>>>(xcatb, 512, 128, 128, Wlb4,
      S4, B4, Tbuf, 256, idxb, xcat + 256, xcatb + 256);

  // ---- head (all bf16 MFMA) ----
  k_mm<2><<<dim3(64, 16), dim3(256), 0, stream>>>(xcatb, 512, 512, Wgb,
      Sg, Bg, nullptr, 1024, nullptr, 0, nullptr, 0, gk);
  k_bias2<<<dim3(256), dim3(256), 0, stream>>>(gk, Ws1, b2g);
  k_mm<1><<<dim3(64, 8), dim3(256), 0, stream>>>(xcatb, 512, 512, Ws1b,
      Ss1, Bs1, b2g, 512, nullptr, 0, h1b, 512, nullptr);
  k_mm<1><<<dim3(64, 4), dim3(256), 0, stream>>>(h1b, 512, 512, Ws2b,
      Ss2, Bs2, nullptr, 256, Tbuf, 256, nullptr, 0, nullptr);
  k_out<<<dim3(512), dim3(256), 0, stream>>>(Tbuf, Ws3, Bs3, (float*)d_out);
}

// Round 8
// 1826.698 us; speedup vs baseline: 1.0237x; 1.0237x over previous
//
#include <hip/hip_runtime.h>
#include <hip/hip_bf16.h>

// DGCNN_Seg forward. B=2, N=4096, K=20. fp32 in/out; bf16 MFMA for layer-4 +
// head GEMMs; fp32 for kNN-feeding path.
// Round 8: k_knn reshaped — JS=8 (1024 blocks), no LDS spill (quad-lane
// in-wave merge), 25.6KB LDS. Selection bit-identical to R5-R7.

#define DEVI static __device__ __forceinline__
typedef __attribute__((ext_vector_type(8))) short bf16x8;   // 8 bf16 = 4 VGPR
typedef __attribute__((ext_vector_type(4))) float f32x4;    // MFMA acc
typedef unsigned long long ull;
#define JS 8  // j-splits per batch in k_knn

DEVI float lrelu(float y) { return y > 0.f ? y : 0.2f * y; }
DEVI unsigned okey(float f) {
  unsigned u = __float_as_uint(f);
  return (f < 0.f) ? ~u : (u | 0x80000000u);
}
DEVI float dekey(unsigned k) {
  return __uint_as_float((k & 0x80000000u) ? (k & 0x7fffffffu) : ~k);
}

// ---------------- weight fp32 -> bf16 pack ----------------
__global__ __launch_bounds__(64) void k_conv(const float* __restrict__ src, int lds, int off,
                                             int sub, int Kc, __hip_bfloat16* __restrict__ dst) {
  int o = blockIdx.x, c = blockIdx.y * 64 + threadIdx.x;
  float v = src[(size_t)o * lds + off + c];
  if (sub) v -= src[(size_t)o * lds + c];
  dst[(size_t)o * Kc + c] = __float2bfloat16(v);
}

// ---------------- row squared-norms: one wave per row ----------------
__global__ __launch_bounds__(256) void k_xx(const float* __restrict__ F, int ldf, int C,
                                            float* __restrict__ xx) {
  int lane = threadIdx.x & 63;
  int row = blockIdx.x * 4 + (threadIdx.x >> 6);
  const float* f = F + (size_t)row * ldf;
  float s = 0.f;
  for (int c = lane; c < C; c += 64) { float v = f[c]; s += v * v; }
#pragma unroll
  for (int off = 32; off; off >>= 1) s += __shfl_xor(s, off, 64);
  if (lane == 0) xx[row] = s;
}

// ---------------- FUSED kNN: dist GEMM tile + online top-20 ----------------
// grid (64 i-tiles, JS j-splits, 2 batches), block 256, 8 j-tiles per block.
// Scan mapping: lane 4r+q of wave w scans quarter q of row w*16+r, keeping a
// per-thread sorted top-20. End: quad-lane shfl merge -> sorted partial per
// (row, j-split). Distances bit-identical to the old k_dist.
__global__ __launch_bounds__(256) void k_knn(const float* __restrict__ F, int ldf, int C,
                                             const float* __restrict__ xx,
                                             ull* __restrict__ part) {
  __shared__ __align__(16) float As[16][68];
  __shared__ __align__(16) float Bs[16][68];
  __shared__ float Dt[64][66];
  const int tid = threadIdx.x;
  const int tx = tid & 15, ty = tid >> 4;
  const int b = blockIdx.z;
  const int i0 = blockIdx.x * 64;
  const int jbase = blockIdx.y * (4096 / JS);
  const float* Fb = F + (size_t)b * 4096 * ldf;
  const float* xxb = xx + b * 4096;
  const int row = tid >> 2, q4 = (tid & 3) * 4;
  const int lane = tid & 63, wv = tid >> 6;
  const int srow = wv * 16 + (lane >> 2), sq = lane & 3;  // scan row / quarter
  ull arr[20];
#pragma unroll
  for (int t = 0; t < 20; ++t) arr[t] = ~0ull;
  float xi[4];
#pragma unroll
  for (int ii = 0; ii < 4; ++ii) xi[ii] = xxb[i0 + ty * 4 + ii];

  for (int jt = 0; jt < 4096 / JS / 64; ++jt) {
    const int j0 = jbase + jt * 64;
    float acc[4][4] = {};
    for (int c0 = 0; c0 < C; c0 += 16) {
      if (C - c0 >= 16) {
        float4 a = *(const float4*)(Fb + (size_t)(i0 + row) * ldf + c0 + q4);
        float4 w = *(const float4*)(Fb + (size_t)(j0 + row) * ldf + c0 + q4);
        As[q4 + 0][row] = a.x; As[q4 + 1][row] = a.y; As[q4 + 2][row] = a.z; As[q4 + 3][row] = a.w;
        Bs[q4 + 0][row] = w.x; Bs[q4 + 1][row] = w.y; Bs[q4 + 2][row] = w.z; Bs[q4 + 3][row] = w.w;
      } else {
#pragma unroll
        for (int e = 0; e < 4; ++e) {
          int c = c0 + q4 + e;
          As[q4 + e][row] = (c < C) ? Fb[(size_t)(i0 + row) * ldf + c] : 0.f;
          Bs[q4 + e][row] = (c < C) ? Fb[(size_t)(j0 + row) * ldf + c] : 0.f;
        }
      }
      __syncthreads();
#pragma unroll
      for (int kk = 0; kk < 16; ++kk) {
        const float4 a4 = *(const float4*)&As[kk][ty * 4];
        const float4 b4 = *(const float4*)&Bs[kk][tx * 4];
        const float av[4] = {a4.x, a4.y, a4.z, a4.w};
        const float bv[4] = {b4.x, b4.y, b4.z, b4.w};
#pragma unroll
        for (int ii = 0; ii < 4; ++ii)
#pragma unroll
          for (int jj = 0; jj < 4; ++jj)
            acc[ii][jj] = fmaf(av[ii], bv[jj], acc[ii][jj]);
      }
      __syncthreads();
    }
    // D tile -> LDS (same formula/order as original k_dist)
#pragma unroll
    for (int ii = 0; ii < 4; ++ii)
#pragma unroll
      for (int jj = 0; jj < 4; ++jj)
        Dt[ty * 4 + ii][tx * 4 + jj] = xi[ii] + xxb[j0 + tx * 4 + jj] - 2.f * acc[ii][jj];
    __syncthreads();
    // scan 16 candidates into per-thread sorted top-20
#pragma unroll
    for (int k = 0; k < 16; ++k) {
      int jl = sq * 16 + k;
      float d = Dt[srow][jl];
      ull key = ((ull)okey(d) << 32) | (unsigned)(j0 + jl);
      if (key < arr[19]) {
#pragma unroll
        for (int t2 = 19; t2 > 0; --t2) {
          bool sh = key < arr[t2 - 1];
          ull c2 = sh ? arr[t2 - 1] : key;
          arr[t2] = (c2 < arr[t2]) ? c2 : arr[t2];
        }
        arr[0] = (key < arr[0]) ? key : arr[0];
      }
    }
    __syncthreads();
  }
  // in-quad 4-way merge (lanes 4r..4r+3), shift-style pop (static indexing)
  ull* op = part + (((size_t)b * 4096 + i0 + srow) * JS + blockIdx.y) * 20;
  for (int o = 0; o < 20; ++o) {
    ull v = arr[0];
    ull m = v;
    ull t1 = __shfl_xor(m, 1, 64); m = t1 < m ? t1 : m;
    ull t2 = __shfl_xor(m, 2, 64); m = t2 < m ? t2 : m;
    bool pop = (v == m);
#pragma unroll
    for (int t = 0; t < 19; ++t) arr[t] = pop ? arr[t + 1] : arr[t];
    if (sq == 0) op[o] = m;
  }
}

// ---------------- merge JS sorted partials per row -> final indices ----------------
__global__ __launch_bounds__(256) void k_kmerge(const ull* __restrict__ part,
                                                int* __restrict__ idx) {
  const int rowg = blockIdx.x * 256 + threadIdx.x;  // 0..8191
  const ull* pr = part + (size_t)rowg * JS * 20;
  int p[JS] = {};
  int* op = idx + (size_t)rowg * 20;
  for (int o = 0; o < 20; ++o) {
    ull best = ~0ull;
    int bq = 0;
#pragma unroll
    for (int q = 0; q < JS; ++q) {
      ull v = pr[q * 20 + p[q]];
      if (v < best) { best = v; bq = q; }
    }
    ++p[bq];
    op[o] = (int)(best & 0xffffffffull);
  }
}

// ---------------- EdgeConv layer 1 (fp32, Cin=3): one wave per point ----------------
__global__ __launch_bounds__(256) void k_edge1(const float* __restrict__ xf,
                                               const float* __restrict__ W1,
                                               const float* __restrict__ s1,
                                               const float* __restrict__ b1,
                                               const int* __restrict__ idx,
                                               float* __restrict__ xcat,
                                               __hip_bfloat16* __restrict__ xcatb) {
  const int lane = threadIdx.x & 63;
  const int p = blockIdx.x * 4 + (threadIdx.x >> 6);
  const int bb = p >> 12;
  float wl[3], wr[3];
#pragma unroll
  for (int c = 0; c < 3; ++c) {
    wl[c] = W1[lane * 6 + c];
    wr[c] = W1[lane * 6 + 3 + c];
  }
  const float s = s1[lane], bi = b1[lane];
  const float* xc = xf + (size_t)p * 3;
  const float x0 = xc[0], x1 = xc[1], x2 = xc[2];
  const float t = x0 * (wr[0] - wl[0]) + x1 * (wr[1] - wl[1]) + x2 * (wr[2] - wl[2]);
  const int* ir = idx + (size_t)p * 20;
  float best = -INFINITY;
  for (int k = 0; k < 20; ++k) {
    int j = ir[k];
    const float* xn = xf + ((size_t)(bb << 12) + j) * 3;
    float y = t + xn[0] * wl[0] + xn[1] * wl[1] + xn[2] * wl[2];
    y = lrelu(y * s + bi);
    best = fmaxf(best, y);
  }
  xcat[(size_t)p * 512 + lane] = best;
  xcatb[(size_t)p * 512 + lane] = __float2bfloat16(best);
}

// ---------------- fp32 pointwise GEMM, raw store (T for layers 2-3) ----------------
__global__ __launch_bounds__(256) void k_pwT(const float* __restrict__ A, int lda, int K,
                                             const float* __restrict__ W, int ldw, int wsub,
                                             float* __restrict__ out, int ldo) {
  __shared__ __align__(16) float As[16][68];
  __shared__ __align__(16) float Bs[16][68];
  const int tid = threadIdx.x;
  const int tx = tid & 15, ty = tid >> 4;
  const int i0 = blockIdx.x * 64, o0 = blockIdx.y * 64;
  const int row = tid >> 2, q = (tid & 3) * 4;
  float acc[4][4] = {};
  for (int c0 = 0; c0 < K; c0 += 16) {
    float4 a = *(const float4*)(A + (size_t)(i0 + row) * lda + c0 + q);
    As[q + 0][row] = a.x; As[q + 1][row] = a.y; As[q + 2][row] = a.z; As[q + 3][row] = a.w;
    const float* wp = W + (size_t)(o0 + row) * ldw + c0 + q;
#pragma unroll
    for (int e = 0; e < 4; ++e) Bs[q + e][row] = wp[wsub + e] - wp[e];
    __syncthreads();
#pragma unroll
    for (int kk = 0; kk < 16; ++kk) {
      const float4 a4 = *(const float4*)&As[kk][ty * 4];
      const float4 b4 = *(const float4*)&Bs[kk][tx * 4];
      const float av[4] = {a4.x, a4.y, a4.z, a4.w};
      const float bv[4] = {b4.x, b4.y, b4.z, b4.w};
#pragma unroll
      for (int ii = 0; ii < 4; ++ii)
#pragma unroll
        for (int jj = 0; jj < 4; ++jj)
          acc[ii][jj] = fmaf(av[ii], bv[jj], acc[ii][jj]);
    }
    __syncthreads();
  }
#pragma unroll
  for (int ii = 0; ii < 4; ++ii)
#pragma unroll
    for (int jj = 0; jj < 4; ++jj)
      out[(size_t)(i0 + ty * 4 + ii) * ldo + o0 + tx * 4 + jj] = acc[ii][jj];
}

// ---------------- fp32 EdgeConv GEMM (layers 2-3; feeds kNN, stays exact) ----------------
__global__ __launch_bounds__(256) void k_edge(const float* __restrict__ F, int ldf, int Cin,
                                              const float* __restrict__ W,
                                              const float* __restrict__ sc,
                                              const float* __restrict__ bi,
                                              const int* __restrict__ idx,
                                              const float* __restrict__ T, int ldt,
                                              float* __restrict__ out,
                                              __hip_bfloat16* __restrict__ outb) {
  __shared__ float As[16][81];
  __shared__ __align__(16) float Bs[16][68];
  __shared__ float Ys[80][65];
  const int tid = threadIdx.x;
  const int tx = tid & 15, ty = tid >> 4;
  const int r0 = blockIdx.x * 80;
  const int o0 = blockIdx.y * 64;
  const int ldw = 2 * Cin;
  int grow[5], gcol[5];
#pragma unroll
  for (int l = 0; l < 5; ++l) {
    int e = tid + l * 256;
    int rr = e >> 4;
    gcol[l] = e & 15;
    int gr = r0 + rr;
    int p = gr / 20;
    int j = idx[(size_t)p * 20 + (gr % 20)];
    grow[l] = ((p >> 12) << 12) + j;
  }
  float acc[5][4] = {};
  const int wrow = tid >> 2, wq = (tid & 3) * 4;
  for (int c0 = 0; c0 < Cin; c0 += 16) {
#pragma unroll
    for (int l = 0; l < 5; ++l) {
      int e = tid + l * 256;
      As[gcol[l]][e >> 4] = F[(size_t)grow[l] * ldf + c0 + gcol[l]];
    }
    {
      const float* wp = W + (size_t)(o0 + wrow) * ldw + c0 + wq;
#pragma unroll
      for (int e = 0; e < 4; ++e) Bs[wq + e][wrow] = wp[e];
    }
    __syncthreads();
#pragma unroll
    for (int kk = 0; kk < 16; ++kk) {
      float a[5];
#pragma unroll
      for (int l = 0; l < 5; ++l) a[l] = As[kk][ty + l * 16];
      const float4 b4 = *(const float4*)&Bs[kk][tx * 4];
      const float bv[4] = {b4.x, b4.y, b4.z, b4.w};
#pragma unroll
      for (int l = 0; l < 5; ++l)
#pragma unroll
        for (int jj = 0; jj < 4; ++jj)
          acc[l][jj] = fmaf(a[l], bv[jj], acc[l][jj]);
    }
    __syncthreads();
  }
#pragma unroll
  for (int l = 0; l < 5; ++l) {
    int r = ty + l * 16;
    int p = (r0 + r) / 20;
#pragma unroll
    for (int jj = 0; jj < 4; ++jj) {
      int o = o0 + tx * 4 + jj;
      float y = (acc[l][jj] + T[(size_t)p * ldt + o]) * sc[o] + bi[o];
      Ys[r][tx * 4 + jj] = lrelu(y);
    }
  }
  __syncthreads();
  const int grp = tid >> 6, col = tid & 63;
  float m = -INFINITY;
#pragma unroll
  for (int k = 0; k < 20; ++k) m = fmaxf(m, Ys[grp * 20 + k][col]);
  const int p = blockIdx.x * 4 + grp;
  out[(size_t)p * 512 + o0 + col] = m;
  outb[(size_t)p * 512 + o0 + col] = __float2bfloat16(m);
}

// ---------------- MFMA bf16 GEMM: block 128(M)x64(N), 4 waves x (32x64) ----------------
template <int EPI>
__global__ __launch_bounds__(256) void k_mm(
    const __hip_bfloat16* __restrict__ A, int lda, int K,
    const __hip_bfloat16* __restrict__ B,  // [N][K] bf16
    const float* __restrict__ sc, const float* __restrict__ bi,
    const float* __restrict__ extra, int Ncols,
    float* __restrict__ outf, int ldof,
    __hip_bfloat16* __restrict__ outb, int ldob,
    unsigned* __restrict__ gmax) {
  __shared__ __align__(16) __hip_bfloat16 Al[128 * 40];
  __shared__ __align__(16) __hip_bfloat16 Bl[64 * 40];
  __shared__ float Red[4][64];
  const int tid = threadIdx.x, lane = tid & 63, wv = tid >> 6;
  const int m0 = blockIdx.x * 128, n0 = blockIdx.y * 64;
  const int arow = tid >> 2, akc = (tid & 3) * 8;
  const int fm = lane & 15, fq = lane >> 4;
  f32x4 acc[2][4];
#pragma unroll
  for (int mt = 0; mt < 2; ++mt)
#pragma unroll
    for (int nt = 0; nt < 4; ++nt) acc[mt][nt] = (f32x4){0.f, 0.f, 0.f, 0.f};
  for (int c0 = 0; c0 < K; c0 += 32) {
#pragma unroll
    for (int l = 0; l < 2; ++l) {
      int r = arow + l * 64;
      *(float4*)&Al[r * 40 + akc] = *(const float4*)(A + (size_t)(m0 + r) * lda + c0 + akc);
    }
    *(float4*)&Bl[arow * 40 + akc] = *(const float4*)(B + (size_t)(n0 + arow) * K + c0 + akc);
    __syncthreads();
    bf16x8 af[2], bfr[4];
#pragma unroll
    for (int mt = 0; mt < 2; ++mt)
      af[mt] = *(const bf16x8*)&Al[(wv * 32 + mt * 16 + fm) * 40 + fq * 8];
#pragma unroll
    for (int nt = 0; nt < 4; ++nt)
      bfr[nt] = *(const bf16x8*)&Bl[(nt * 16 + fm) * 40 + fq * 8];
#pragma unroll
    for (int mt = 0; mt < 2; ++mt)
#pragma unroll
      for (int nt = 0; nt < 4; ++nt)
        acc[mt][nt] = __builtin_amdgcn_mfma_f32_16x16x32_bf16(af[mt], bfr[nt], acc[mt][nt], 0, 0, 0);
    __syncthreads();
  }
  const int bidx = m0 >> 12;
  if (EPI == 0) {
#pragma unroll
    for (int mt = 0; mt < 2; ++mt)
#pragma unroll
      for (int nt = 0; nt < 4; ++nt)
#pragma unroll
        for (int r = 0; r < 4; ++r)
          outf[(size_t)(m0 + wv * 32 + mt * 16 + fq * 4 + r) * ldof + n0 + nt * 16 + fm] =
              acc[mt][nt][r];
  } else if (EPI == 1) {
#pragma unroll
    for (int nt = 0; nt < 4; ++nt) {
      int col = n0 + nt * 16 + fm;
      float s = sc[col], bb = bi[col];
      float ex = extra ? extra[bidx * Ncols + col] : 0.f;
#pragma unroll
      for (int mt = 0; mt < 2; ++mt)
#pragma unroll
        for (int r = 0; r < 4; ++r) {
          float v = lrelu((acc[mt][nt][r] + ex) * s + bb);
          size_t rr = (size_t)(m0 + wv * 32 + mt * 16 + fq * 4 + r);
          if (outf) outf[rr * ldof + col] = v;
          if (outb) outb[rr * ldob + col] = __float2bfloat16(v);
        }
    }
  } else {
#pragma unroll
    for (int nt = 0; nt < 4; ++nt) {
      int col = n0 + nt * 16 + fm;
      float s = sc[col], bb = bi[col];
      float m = -INFINITY;
#pragma unroll
      for (int mt = 0; mt < 2; ++mt)
#pragma unroll
        for (int r = 0; r < 4; ++r) m = fmaxf(m, lrelu(acc[mt][nt][r] * s + bb));
      m = fmaxf(m, __shfl_xor(m, 16, 64));
      m = fmaxf(m, __shfl_xor(m, 32, 64));
      if (fq == 0) Red[wv][nt * 16 + fm] = m;
    }
    __syncthreads();
    if (tid < 64) {
      float m = fmaxf(fmaxf(Red[0][tid], Red[1][tid]), fmaxf(Red[2][tid], Red[3][tid]));
      atomicMax(&gmax[bidx * Ncols + n0 + tid], okey(m));
    }
  }
}

// ---------------- MFMA bf16 EdgeConv (layer 4): 320 edges x 64 cols / block ----------------
__global__ __launch_bounds__(256) void k_edgem(
    const __hip_bfloat16* __restrict__ F, int ldf, int coff, int K,
    const __hip_bfloat16* __restrict__ Wl,  // [N][K] bf16
    const float* __restrict__ sc, const float* __restrict__ bi,
    const float* __restrict__ T, int N,
    const int* __restrict__ idx,
    float* __restrict__ outf, __hip_bfloat16* __restrict__ outb) {
  __shared__ __align__(16) char smem[320 * 66 * 2];  // 42240 B, overlaid stage/Ys
  __hip_bfloat16* Al = (__hip_bfloat16*)smem;              // 320*40
  __hip_bfloat16* Bl = (__hip_bfloat16*)(smem + 25600);    // 64*40
  __hip_bfloat16* Ys = (__hip_bfloat16*)smem;              // 320*66 (post-loop)
  const int tid = threadIdx.x, lane = tid & 63, wv = tid >> 6;
  const int blk = blockIdx.x, n0 = blockIdx.y * 64;
  const int arow = tid >> 2, akc = (tid & 3) * 8;
  const int fm = lane & 15, fq = lane >> 4;
  const __hip_bfloat16* ap[5];
#pragma unroll
  for (int l = 0; l < 5; ++l) {
    int row = arow + l * 64;
    int e = blk * 320 + row;
    int p = e / 20;
    int j = idx[(size_t)p * 20 + (e - p * 20)];
    int src = ((p >> 12) << 12) + j;
    ap[l] = F + (size_t)src * ldf + coff + akc;
  }
  f32x4 acc[5][4];
#pragma unroll
  for (int l = 0; l < 5; ++l)
#pragma unroll
    for (int nt = 0; nt < 4; ++nt) acc[l][nt] = (f32x4){0.f, 0.f, 0.f, 0.f};
  for (int c0 = 0; c0 < K; c0 += 32) {
#pragma unroll
    for (int l = 0; l < 5; ++l)
      *(float4*)&Al[(arow + l * 64) * 40 + akc] = *(const float4*)(ap[l] + c0);
    *(float4*)&Bl[arow * 40 + akc] = *(const float4*)(Wl + (size_t)(n0 + arow) * K + c0 + akc);
    __syncthreads();
    bf16x8 af[5], bfr[4];
#pragma unroll
    for (int l = 0; l < 5; ++l)
      af[l] = *(const bf16x8*)&Al[(wv * 80 + l * 16 + fm) * 40 + fq * 8];
#pragma unroll
    for (int nt = 0; nt < 4; ++nt)
      bfr[nt] = *(const bf16x8*)&Bl[(nt * 16 + fm) * 40 + fq * 8];
#pragma unroll
    for (int l = 0; l < 5; ++l)
#pragma unroll
      for (int nt = 0; nt < 4; ++nt)
        acc[l][nt] = __builtin_amdgcn_mfma_f32_16x16x32_bf16(af[l], bfr[nt], acc[l][nt], 0, 0, 0);
    __syncthreads();
  }
#pragma unroll
  for (int l = 0; l < 5; ++l)
#pragma unroll
    for (int nt = 0; nt < 4; ++nt)
#pragma unroll
      for (int r = 0; r < 4; ++r)
        Ys[(wv * 80 + l * 16 + fq * 4 + r) * 66 + nt * 16 + fm] = __float2bfloat16(acc[l][nt][r]);
  __syncthreads();
  const int col = tid & 63;
#pragma unroll
  for (int gi = 0; gi < 4; ++gi) {
    int grp = wv + gi * 4;
    float m = -INFINITY;
#pragma unroll
    for (int k = 0; k < 20; ++k)
      m = fmaxf(m, __bfloat162float(Ys[(grp * 20 + k) * 66 + col]));
    int p = blk * 16 + grp;
    int o = n0 + col;
    float v = lrelu((m + T[(size_t)p * N + o]) * sc[o] + bi[o]);
    outf[(size_t)p * 512 + o] = v;
    outb[(size_t)p * 512 + o] = __float2bfloat16(v);
  }
}

// ---------------- bias2: one wave per (b,o) ----------------
__global__ __launch_bounds__(256) void k_bias2(const unsigned* __restrict__ gk,
                                               const float* __restrict__ Ws1,
                                               float* __restrict__ b2g) {
  const int lane = threadIdx.x & 63;
  const int wid = (blockIdx.x * 256 + threadIdx.x) >> 6;  // 0..1023
  const int b = wid >> 9, o = wid & 511;
  const float* wr = Ws1 + (size_t)o * 1536 + 512;
  const unsigned* g = gk + b * 1024;
  float acc = 0.f;
#pragma unroll
  for (int c = lane; c < 1024; c += 64) acc = fmaf(dekey(g[c]), wr[c], acc);
#pragma unroll
  for (int off = 32; off; off >>= 1) acc += __shfl_xor(acc, off, 64);
  if (lane == 0) b2g[b * 512 + o] = acc;
}

// ---------------- final head: out = H(8192x256) . Ws3^T + bs3 (fp32) ----------------
__global__ __launch_bounds__(256) void k_out(const float* __restrict__ H,
                                             const float* __restrict__ Ws3,
                                             const float* __restrict__ bs3,
                                             float* __restrict__ out) {
  __shared__ float Ws[13][256];
  const int tid = threadIdx.x;
  for (int e = tid; e < 13 * 256; e += 256) Ws[e >> 8][e & 255] = Ws3[e];
  __syncthreads();
  const int rloc = tid >> 4, o = tid & 15;
  const int row = blockIdx.x * 16 + rloc;
  if (o < 13) {
    const float* h = H + (size_t)row * 256;
    float acc = 0.f;
    for (int c = 0; c < 256; ++c) acc = fmaf(h[c], Ws[o][c], acc);
    out[(size_t)row * 13 + o] = acc + bs3[o];
  }
}

extern "C" void kernel_launch(void* const* d_in, const int* in_sizes, int n_in,
                              void* d_out, int out_size, void* d_ws, size_t ws_size,
                              hipStream_t stream) {
  const float* X   = (const float*)d_in[0];
  const float* W1  = (const float*)d_in[1];
  const float* S1  = (const float*)d_in[2];
  const float* B1  = (const float*)d_in[3];
  const float* W2  = (const float*)d_in[4];
  const float* S2  = (const float*)d_in[5];
  const float* B2  = (const float*)d_in[6];
  const float* W3  = (const float*)d_in[7];
  const float* S3  = (const float*)d_in[8];
  const float* B3  = (const float*)d_in[9];
  const float* W4  = (const float*)d_in[10];
  const float* S4  = (const float*)d_in[11];
  const float* B4  = (const float*)d_in[12];
  const float* Wg  = (const float*)d_in[13];
  const float* Sg  = (const float*)d_in[14];
  const float* Bg  = (const float*)d_in[15];
  const float* Ws1 = (const float*)d_in[16];
  const float* Ss1 = (const float*)d_in[17];
  const float* Bs1 = (const float*)d_in[18];
  const float* Ws2 = (const float*)d_in[19];
  const float* Ss2 = (const float*)d_in[20];
  const float* Bs2 = (const float*)d_in[21];
  const float* Ws3 = (const float*)d_in[22];
  const float* Bs3 = (const float*)d_in[23];

  char* ws = (char*)d_ws;
  float*           xxb   = (float*)(ws + 0);            // 32 KB
  int*             idxb  = (int*)(ws + 32768);          // 640 KB
  unsigned*        gk    = (unsigned*)(ws + 688128);    // 8 KB
  float*           b2g   = (float*)(ws + 696320);       // 4 KB
  __hip_bfloat16*  Wgb   = (__hip_bfloat16*)(ws + 1048576);  // 1 MB
  __hip_bfloat16*  Ws1b  = (__hip_bfloat16*)(ws + 2097152);  // 512 KB
  __hip_bfloat16*  Ws2b  = (__hip_bfloat16*)(ws + 2621440);  // 256 KB
  __hip_bfloat16*  Wlb4  = (__hip_bfloat16*)(ws + 2883584);  // 64 KB
  __hip_bfloat16*  Wdb4  = (__hip_bfloat16*)(ws + 2949120);  // 64 KB
  __hip_bfloat16*  xcatb = (__hip_bfloat16*)(ws + 3145728);  // 8 MB
  float*           xcat  = (float*)(ws + 11534336);          // 16 MB
  char*            region = ws + 28311552;                   // 16 MB shared
  ull*             part  = (ull*)(region);                    // kNN: 8192*JS*20*8 = 10.5 MB
  float*           Tbuf  = (float*)(region);                  // post-kNN per layer: T / h2
  __hip_bfloat16*  h1b   = (__hip_bfloat16*)(region + 8388608);  // head phase only

  hipMemsetAsync(gk, 0, 2 * 1024 * sizeof(unsigned), stream);

  // weight bf16 packs
  k_conv<<<dim3(256, 2), dim3(64), 0, stream>>>(W4, 256, 0, 0, 128, Wlb4);
  k_conv<<<dim3(256, 2), dim3(64), 0, stream>>>(W4, 256, 128, 1, 128, Wdb4);
  k_conv<<<dim3(1024, 8), dim3(64), 0, stream>>>(Wg, 512, 0, 0, 512, Wgb);
  k_conv<<<dim3(512, 8), dim3(64), 0, stream>>>(Ws1, 1536, 0, 0, 512, Ws1b);
  k_conv<<<dim3(256, 8), dim3(64), 0, stream>>>(Ws2, 512, 0, 0, 512, Ws2b);

  // ---- Layer 1 (C=3 -> 64) ----
  k_xx<<<dim3(2048), dim3(256), 0, stream>>>(X, 3, 3, xxb);
  k_knn<<<dim3(64, JS, 2), dim3(256), 0, stream>>>(X, 3, 3, xxb, part);
  k_kmerge<<<dim3(32), dim3(256), 0, stream>>>(part, idxb);
  k_edge1<<<dim3(2048), dim3(256), 0, stream>>>(X, W1, S1, B1, idxb, xcat, xcatb);

  // ---- Layer 2 (64 -> 64), fp32 (feeds kNN) ----
  k_xx<<<dim3(2048), dim3(256), 0, stream>>>(xcat, 512, 64, xxb);
  k_knn<<<dim3(64, JS, 2), dim3(256), 0, stream>>>(xcat, 512, 64, xxb, part);
  k_kmerge<<<dim3(32), dim3(256), 0, stream>>>(part, idxb);
  k_pwT<<<dim3(128, 1), dim3(256), 0, stream>>>(xcat, 512, 64, W2, 128, 64, Tbuf, 64);
  k_edge<<<dim3(2048, 1), dim3(256), 0, stream>>>(xcat, 512, 64, W2, S2, B2,
      idxb, Tbuf, 64, xcat + 64, xcatb + 64);

  // ---- Layer 3 (64 -> 128), fp32 (feeds kNN) ----
  k_xx<<<dim3(2048), dim3(256), 0, stream>>>(xcat + 64, 512, 64, xxb);
  k_knn<<<dim3(64, JS, 2), dim3(256), 0, stream>>>(xcat + 64, 512, 64, xxb, part);
  k_kmerge<<<dim3(32), dim3(256), 0, stream>>>(part, idxb);
  k_pwT<<<dim3(128, 2), dim3(256), 0, stream>>>(xcat + 64, 512, 64, W3, 128, 64, Tbuf, 128);
  k_edge<<<dim3(2048, 2), dim3(256), 0, stream>>>(xcat + 64, 512, 64, W3, S3, B3,
      idxb, Tbuf, 128, xcat + 128, xcatb + 128);

  // ---- Layer 4 (128 -> 256), bf16 MFMA ----
  k_xx<<<dim3(2048), dim3(256), 0, stream>>>(xcat + 128, 512, 128, xxb);
  k_knn<<<dim3(64, JS, 2), dim3(256), 0, stream>>>(xcat + 128, 512, 128, xxb, part);
  k_kmerge<<<dim3(32), dim3(256), 0, stream>>>(part, idxb);
  k_mm<0><<<dim3(64, 4), dim3(256), 0, stream>>>(xcatb + 128, 512, 128, Wdb4,
      nullptr, nullptr, nullptr, 256, Tbuf, 256, nullptr, 0, nullptr);
  k_edgem<<<dim3(512, 4), dim3(256), 0, stream>>>(xcatb, 512, 128, 128, Wlb4,
      S4, B4, Tbuf, 256, idxb, xcat + 256, xcatb + 256);

  // ---- head (all bf16 MFMA) ----
  k_mm<2><<<dim3(64, 16), dim3(256), 0, stream>>>(xcatb, 512, 512, Wgb,
      Sg, Bg, nullptr, 1024, nullptr, 0, nullptr, 0, gk);
  k_bias2<<<dim3(256), dim3(256), 0, stream>>>(gk, Ws1, b2g);
  k_mm<1><<<dim3(64, 8), dim3(256), 0, stream>>>(xcatb, 512, 512, Ws1b,
      Ss1, Bs1, b2g, 512, nullptr, 0, h1b, 512, nullptr);
  k_mm<1><<<dim3(64, 4), dim3(256), 0, stream>>>(h1b, 512, 512, Ws2b,
      Ss2, Bs2, nullptr, 256, Tbuf, 256, nullptr, 0, nullptr);
  k_out<<<dim3(512), dim3(256), 0, stream>>>(Tbuf, Ws3, Bs3, (float*)d_out);
}

// Round 10
// 1168.795 us; speedup vs baseline: 1.5999x; 1.5629x over previous
//
#include <hip/hip_runtime.h>
#include <hip/hip_bf16.h>

// DGCNN_Seg forward. B=2, N=4096, K=20. fp32 in/out.
// Round 10: R6 pipeline (best valid: 1450us, absmax 0.0117) + full-batch
// 64MB dist buffer (4 kNN dispatches/layer instead of 16; selection
// bit-identical). R9's bf16 L2/L3 gamble FAILED (absmax 0.078) -> layers 1-3
// stay fp32-exact; only L4+head use bf16 MFMA.

#define DEVI static __device__ __forceinline__
typedef __attribute__((ext_vector_type(8))) short bf16x8;   // 8 bf16 = 4 VGPR
typedef __attribute__((ext_vector_type(4))) float f32x4;    // MFMA acc
typedef unsigned long long ull;

DEVI float lrelu(float y) { return y > 0.f ? y : 0.2f * y; }
DEVI unsigned okey(float f) {
  unsigned u = __float_as_uint(f);
  return (f < 0.f) ? ~u : (u | 0x80000000u);
}
DEVI float dekey(unsigned k) {
  return __uint_as_float((k & 0x80000000u) ? (k & 0x7fffffffu) : ~k);
}

// ---------------- weight fp32 -> bf16 pack ----------------
__global__ __launch_bounds__(64) void k_conv(const float* __restrict__ src, int lds, int off,
                                             int sub, int Kc, __hip_bfloat16* __restrict__ dst) {
  int o = blockIdx.x, c = blockIdx.y * 64 + threadIdx.x;
  float v = src[(size_t)o * lds + off + c];
  if (sub) v -= src[(size_t)o * lds + c];
  dst[(size_t)o * Kc + c] = __float2bfloat16(v);
}

// ---------------- row squared-norms: one wave per row ----------------
__global__ __launch_bounds__(256) void k_xx(const float* __restrict__ F, int ldf, int C,
                                            float* __restrict__ xx) {
  int lane = threadIdx.x & 63;
  int row = blockIdx.x * 4 + (threadIdx.x >> 6);
  const float* f = F + (size_t)row * ldf;
  float s = 0.f;
  for (int c = lane; c < C; c += 64) { float v = f[c]; s += v * v; }
#pragma unroll
  for (int off = 32; off; off >>= 1) s += __shfl_xor(s, off, 64);
  if (lane == 0) xx[row] = s;
}

// ---------------- pairwise distances, row-chunk of one batch (fp32) ----------------
__global__ __launch_bounds__(256) void k_dist(const float* __restrict__ F, int ldf, int C,
                                              const float* __restrict__ xx,
                                              float* __restrict__ D, int b, int ibase) {
  __shared__ __align__(16) float As[16][68];
  __shared__ __align__(16) float Bs[16][68];
  const int tid = threadIdx.x;
  const int tx = tid & 15, ty = tid >> 4;
  const int i0 = ibase + blockIdx.x * 64, j0 = blockIdx.y * 64;
  const float* Fb = F + (size_t)b * 4096 * ldf;
  const int row = tid >> 2, q = (tid & 3) * 4;
  float acc[4][4] = {};
  for (int c0 = 0; c0 < C; c0 += 16) {
    if (C - c0 >= 16) {
      float4 a = *(const float4*)(Fb + (size_t)(i0 + row) * ldf + c0 + q);
      float4 w = *(const float4*)(Fb + (size_t)(j0 + row) * ldf + c0 + q);
      As[q + 0][row] = a.x; As[q + 1][row] = a.y; As[q + 2][row] = a.z; As[q + 3][row] = a.w;
      Bs[q + 0][row] = w.x; Bs[q + 1][row] = w.y; Bs[q + 2][row] = w.z; Bs[q + 3][row] = w.w;
    } else {
#pragma unroll
      for (int e = 0; e < 4; ++e) {
        int c = c0 + q + e;
        As[q + e][row] = (c < C) ? Fb[(size_t)(i0 + row) * ldf + c] : 0.f;
        Bs[q + e][row] = (c < C) ? Fb[(size_t)(j0 + row) * ldf + c] : 0.f;
      }
    }
    __syncthreads();
#pragma unroll
    for (int kk = 0; kk < 16; ++kk) {
      const float4 a4 = *(const float4*)&As[kk][ty * 4];
      const float4 b4 = *(const float4*)&Bs[kk][tx * 4];
      const float av[4] = {a4.x, a4.y, a4.z, a4.w};
      const float bv[4] = {b4.x, b4.y, b4.z, b4.w};
#pragma unroll
      for (int ii = 0; ii < 4; ++ii)
#pragma unroll
        for (int jj = 0; jj < 4; ++jj)
          acc[ii][jj] = fmaf(av[ii], bv[jj], acc[ii][jj]);
    }
    __syncthreads();
  }
  const float* xxb = xx + b * 4096;
#pragma unroll
  for (int ii = 0; ii < 4; ++ii) {
    int i = i0 + ty * 4 + ii;
    float xi = xxb[i];
#pragma unroll
    for (int jj = 0; jj < 4; ++jj) {
      int j = j0 + tx * 4 + jj;
      D[(size_t)(i - ibase) * 4096 + j] = xi + xxb[j] - 2.f * acc[ii][jj];
    }
  }
}

// ---------------- top-20 smallest per row: 1 block (4 waves) per row ----------------
__global__ __launch_bounds__(256) void k_topk(const float* __restrict__ D,
                                              int* __restrict__ idx, int b, int ibase) {
  __shared__ ull sarr[4 * 64 * 17];
  __shared__ ull cand[4][20];
  const int tid = threadIdx.x, lane = tid & 63, wv = tid >> 6;
  const int ir_ = blockIdx.x;
  const float* drow = D + (size_t)ir_ * 4096;
  ull arr[16];
  const int base = wv * 1024 + lane;
#pragma unroll
  for (int it = 0; it < 16; ++it) {
    int j = base + it * 64;
    float d = drow[j];
    arr[it] = ((ull)okey(d) << 32) | (unsigned)j;
  }
#pragma unroll
  for (int k = 2; k <= 16; k <<= 1) {
#pragma unroll
    for (int jj = k >> 1; jj > 0; jj >>= 1) {
#pragma unroll
      for (int i = 0; i < 16; ++i) {
        int l = i ^ jj;
        if (l > i) {
          bool up = ((i & k) == 0);
          bool sw = (arr[i] > arr[l]) == up;
          ull a = arr[i], bb = arr[l];
          arr[i] = sw ? bb : a;
          arr[l] = sw ? a : bb;
        }
      }
    }
  }
  ull* myl = &sarr[(wv * 64 + lane) * 17];
#pragma unroll
  for (int t = 0; t < 16; ++t) myl[t] = arr[t];
  ull cur = arr[0], nxt = arr[1];
  int nidx = 2;
  for (int r = 0; r < 20; ++r) {
    unsigned hi = (unsigned)(cur >> 32), lo = (unsigned)cur;
    unsigned mh = hi;
#pragma unroll
    for (int off = 32; off; off >>= 1) {
      unsigned o = __shfl_xor(mh, off, 64);
      mh = o < mh ? o : mh;
    }
    unsigned lo2 = (hi == mh) ? lo : 0xFFFFFFFFu;
    unsigned ml = lo2;
#pragma unroll
    for (int off = 32; off; off >>= 1) {
      unsigned o = __shfl_xor(ml, off, 64);
      ml = o < ml ? o : ml;
    }
    if (lane == 0) cand[wv][r] = ((ull)mh << 32) | ml;
    bool pop = (hi == mh) && (lo == ml);
    if (pop) {
      cur = nxt;
      nxt = (nidx < 16) ? myl[nidx] : ~0ull;
      ++nidx;
    }
  }
  __syncthreads();
  if (tid == 0) {
    int* op = idx + ((size_t)b * 4096 + ibase + ir_) * 20;
    int p0 = 0, p1 = 0, p2 = 0, p3 = 0;
    for (int r = 0; r < 20; ++r) {
      ull v0 = cand[0][p0], v1 = cand[1][p1], v2 = cand[2][p2], v3 = cand[3][p3];
      ull m01 = v0 < v1 ? v0 : v1;
      ull m23 = v2 < v3 ? v2 : v3;
      ull best = m01 < m23 ? m01 : m23;
      if (best == v0) ++p0; else if (best == v1) ++p1;
      else if (best == v2) ++p2; else ++p3;
      op[r] = (int)(best & 0xffffffffull);
      if (p0 > 19) p0 = 19;
      if (p1 > 19) p1 = 19;
      if (p2 > 19) p2 = 19;
      if (p3 > 19) p3 = 19;
    }
  }
}

// ---------------- EdgeConv layer 1 (fp32, Cin=3): one wave per point ----------------
__global__ __launch_bounds__(256) void k_edge1(const float* __restrict__ xf,
                                               const float* __restrict__ W1,
                                               const float* __restrict__ s1,
                                               const float* __restrict__ b1,
                                               const int* __restrict__ idx,
                                               float* __restrict__ xcat,
                                               __hip_bfloat16* __restrict__ xcatb) {
  const int lane = threadIdx.x & 63;
  const int p = blockIdx.x * 4 + (threadIdx.x >> 6);
  const int bb = p >> 12;
  float wl[3], wr[3];
#pragma unroll
  for (int c = 0; c < 3; ++c) {
    wl[c] = W1[lane * 6 + c];
    wr[c] = W1[lane * 6 + 3 + c];
  }
  const float s = s1[lane], bi = b1[lane];
  const float* xc = xf + (size_t)p * 3;
  const float x0 = xc[0], x1 = xc[1], x2 = xc[2];
  const float t = x0 * (wr[0] - wl[0]) + x1 * (wr[1] - wl[1]) + x2 * (wr[2] - wl[2]);
  const int* ir = idx + (size_t)p * 20;
  float best = -INFINITY;
  for (int k = 0; k < 20; ++k) {
    int j = ir[k];
    const float* xn = xf + ((size_t)(bb << 12) + j) * 3;
    float y = t + xn[0] * wl[0] + xn[1] * wl[1] + xn[2] * wl[2];
    y = lrelu(y * s + bi);
    best = fmaxf(best, y);
  }
  xcat[(size_t)p * 512 + lane] = best;
  xcatb[(size_t)p * 512 + lane] = __float2bfloat16(best);
}

// ---------------- fp32 pointwise GEMM, raw store (T for layers 2-3) ----------------
__global__ __launch_bounds__(256) void k_pwT(const float* __restrict__ A, int lda, int K,
                                             const float* __restrict__ W, int ldw, int wsub,
                                             float* __restrict__ out, int ldo) {
  __shared__ __align__(16) float As[16][68];
  __shared__ __align__(16) float Bs[16][68];
  const int tid = threadIdx.x;
  const int tx = tid & 15, ty = tid >> 4;
  const int i0 = blockIdx.x * 64, o0 = blockIdx.y * 64;
  const int row = tid >> 2, q = (tid & 3) * 4;
  float acc[4][4] = {};
  for (int c0 = 0; c0 < K; c0 += 16) {
    float4 a = *(const float4*)(A + (size_t)(i0 + row) * lda + c0 + q);
    As[q + 0][row] = a.x; As[q + 1][row] = a.y; As[q + 2][row] = a.z; As[q + 3][row] = a.w;
    const float* wp = W + (size_t)(o0 + row) * ldw + c0 + q;
#pragma unroll
    for (int e = 0; e < 4; ++e) Bs[q + e][row] = wp[wsub + e] - wp[e];
    __syncthreads();
#pragma unroll
    for (int kk = 0; kk < 16; ++kk) {
      const float4 a4 = *(const float4*)&As[kk][ty * 4];
      const float4 b4 = *(const float4*)&Bs[kk][tx * 4];
      const float av[4] = {a4.x, a4.y, a4.z, a4.w};
      const float bv[4] = {b4.x, b4.y, b4.z, b4.w};
#pragma unroll
      for (int ii = 0; ii < 4; ++ii)
#pragma unroll
        for (int jj = 0; jj < 4; ++jj)
          acc[ii][jj] = fmaf(av[ii], bv[jj], acc[ii][jj]);
    }
    __syncthreads();
  }
#pragma unroll
  for (int ii = 0; ii < 4; ++ii)
#pragma unroll
    for (int jj = 0; jj < 4; ++jj)
      out[(size_t)(i0 + ty * 4 + ii) * ldo + o0 + tx * 4 + jj] = acc[ii][jj];
}

// ---------------- fp32 EdgeConv GEMM (layers 2-3; feeds kNN, stays exact) ----------------
__global__ __launch_bounds__(256) void k_edge(const float* __restrict__ F, int ldf, int Cin,
                                              const float* __restrict__ W,
                                              const float* __restrict__ sc,
                                              const float* __restrict__ bi,
                                              const int* __restrict__ idx,
                                              const float* __restrict__ T, int ldt,
                                              float* __restrict__ out,
                                              __hip_bfloat16* __restrict__ outb) {
  __shared__ float As[16][81];
  __shared__ __align__(16) float Bs[16][68];
  __shared__ float Ys[80][65];
  const int tid = threadIdx.x;
  const int tx = tid & 15, ty = tid >> 4;
  const int r0 = blockIdx.x * 80;
  const int o0 = blockIdx.y * 64;
  const int ldw = 2 * Cin;
  int grow[5], gcol[5];
#pragma unroll
  for (int l = 0; l < 5; ++l) {
    int e = tid + l * 256;
    int rr = e >> 4;
    gcol[l] = e & 15;
    int gr = r0 + rr;
    int p = gr / 20;
    int j = idx[(size_t)p * 20 + (gr % 20)];
    grow[l] = ((p >> 12) << 12) + j;
  }
  float acc[5][4] = {};
  const int wrow = tid >> 2, wq = (tid & 3) * 4;
  for (int c0 = 0; c0 < Cin; c0 += 16) {
#pragma unroll
    for (int l = 0; l < 5; ++l) {
      int e = tid + l * 256;
      As[gcol[l]][e >> 4] = F[(size_t)grow[l] * ldf + c0 + gcol[l]];
    }
    {
      const float* wp = W + (size_t)(o0 + wrow) * ldw + c0 + wq;
#pragma unroll
      for (int e = 0; e < 4; ++e) Bs[wq + e][wrow] = wp[e];
    }
    __syncthreads();
#pragma unroll
    for (int kk = 0; kk < 16; ++kk) {
      float a[5];
#pragma unroll
      for (int l = 0; l < 5; ++l) a[l] = As[kk][ty + l * 16];
      const float4 b4 = *(const float4*)&Bs[kk][tx * 4];
      const float bv[4] = {b4.x, b4.y, b4.z, b4.w};
#pragma unroll
      for (int l = 0; l < 5; ++l)
#pragma unroll
        for (int jj = 0; jj < 4; ++jj)
          acc[l][jj] = fmaf(a[l], bv[jj], acc[l][jj]);
    }
    __syncthreads();
  }
#pragma unroll
  for (int l = 0; l < 5; ++l) {
    int r = ty + l * 16;
    int p = (r0 + r) / 20;
#pragma unroll
    for (int jj = 0; jj < 4; ++jj) {
      int o = o0 + tx * 4 + jj;
      float y = (acc[l][jj] + T[(size_t)p * ldt + o]) * sc[o] + bi[o];
      Ys[r][tx * 4 + jj] = lrelu(y);
    }
  }
  __syncthreads();
  const int grp = tid >> 6, col = tid & 63;
  float m = -INFINITY;
#pragma unroll
  for (int k = 0; k < 20; ++k) m = fmaxf(m, Ys[grp * 20 + k][col]);
  const int p = blockIdx.x * 4 + grp;
  out[(size_t)p * 512 + o0 + col] = m;
  outb[(size_t)p * 512 + o0 + col] = __float2bfloat16(m);
}

// ---------------- MFMA bf16 GEMM: block 128(M)x64(N), 4 waves x (32x64) ----------------
template <int EPI>
__global__ __launch_bounds__(256) void k_mm(
    const __hip_bfloat16* __restrict__ A, int lda, int K,
    const __hip_bfloat16* __restrict__ B,  // [N][K] bf16
    const float* __restrict__ sc, const float* __restrict__ bi,
    const float* __restrict__ extra, int Ncols,
    float* __restrict__ outf, int ldof,
    __hip_bfloat16* __restrict__ outb, int ldob,
    unsigned* __restrict__ gmax) {
  __shared__ __align__(16) __hip_bfloat16 Al[128 * 40];
  __shared__ __align__(16) __hip_bfloat16 Bl[64 * 40];
  __shared__ float Red[4][64];
  const int tid = threadIdx.x, lane = tid & 63, wv = tid >> 6;
  const int m0 = blockIdx.x * 128, n0 = blockIdx.y * 64;
  const int arow = tid >> 2, akc = (tid & 3) * 8;
  const int fm = lane & 15, fq = lane >> 4;
  f32x4 acc[2][4];
#pragma unroll
  for (int mt = 0; mt < 2; ++mt)
#pragma unroll
    for (int nt = 0; nt < 4; ++nt) acc[mt][nt] = (f32x4){0.f, 0.f, 0.f, 0.f};
  for (int c0 = 0; c0 < K; c0 += 32) {
#pragma unroll
    for (int l = 0; l < 2; ++l) {
      int r = arow + l * 64;
      *(float4*)&Al[r * 40 + akc] = *(const float4*)(A + (size_t)(m0 + r) * lda + c0 + akc);
    }
    *(float4*)&Bl[arow * 40 + akc] = *(const float4*)(B + (size_t)(n0 + arow) * K + c0 + akc);
    __syncthreads();
    bf16x8 af[2], bfr[4];
#pragma unroll
    for (int mt = 0; mt < 2; ++mt)
      af[mt] = *(const bf16x8*)&Al[(wv * 32 + mt * 16 + fm) * 40 + fq * 8];
#pragma unroll
    for (int nt = 0; nt < 4; ++nt)
      bfr[nt] = *(const bf16x8*)&Bl[(nt * 16 + fm) * 40 + fq * 8];
#pragma unroll
    for (int mt = 0; mt < 2; ++mt)
#pragma unroll
      for (int nt = 0; nt < 4; ++nt)
        acc[mt][nt] = __builtin_amdgcn_mfma_f32_16x16x32_bf16(af[mt], bfr[nt], acc[mt][nt], 0, 0, 0);
    __syncthreads();
  }
  const int bidx = m0 >> 12;
  if (EPI == 0) {
#pragma unroll
    for (int mt = 0; mt < 2; ++mt)
#pragma unroll
      for (int nt = 0; nt < 4; ++nt)
#pragma unroll
        for (int r = 0; r < 4; ++r)
          outf[(size_t)(m0 + wv * 32 + mt * 16 + fq * 4 + r) * ldof + n0 + nt * 16 + fm] =
              acc[mt][nt][r];
  } else if (EPI == 1) {
#pragma unroll
    for (int nt = 0; nt < 4; ++nt) {
      int col = n0 + nt * 16 + fm;
      float s = sc[col], bb = bi[col];
      float ex = extra ? extra[bidx * Ncols + col] : 0.f;
#pragma unroll
      for (int mt = 0; mt < 2; ++mt)
#pragma unroll
        for (int r = 0; r < 4; ++r) {
          float v = lrelu((acc[mt][nt][r] + ex) * s + bb);
          size_t rr = (size_t)(m0 + wv * 32 + mt * 16 + fq * 4 + r);
          if (outf) outf[rr * ldof + col] = v;
          if (outb) outb[rr * ldob + col] = __float2bfloat16(v);
        }
    }
  } else {
#pragma unroll
    for (int nt = 0; nt < 4; ++nt) {
      int col = n0 + nt * 16 + fm;
      float s = sc[col], bb = bi[col];
      float m = -INFINITY;
#pragma unroll
      for (int mt = 0; mt < 2; ++mt)
#pragma unroll
        for (int r = 0; r < 4; ++r) m = fmaxf(m, lrelu(acc[mt][nt][r] * s + bb));
      m = fmaxf(m, __shfl_xor(m, 16, 64));
      m = fmaxf(m, __shfl_xor(m, 32, 64));
      if (fq == 0) Red[wv][nt * 16 + fm] = m;
    }
    __syncthreads();
    if (tid < 64) {
      float m = fmaxf(fmaxf(Red[0][tid], Red[1][tid]), fmaxf(Red[2][tid], Red[3][tid]));
      atomicMax(&gmax[bidx * Ncols + n0 + tid], okey(m));
    }
  }
}

// ---------------- MFMA bf16 EdgeConv (layer 4): 320 edges x 64 cols / block ----------------
__global__ __launch_bounds__(256) void k_edgem(
    const __hip_bfloat16* __restrict__ F, int ldf, int coff, int K,
    const __hip_bfloat16* __restrict__ Wl,  // [N][K] bf16
    const float* __restrict__ sc, const float* __restrict__ bi,
    const float* __restrict__ T, int N,
    const int* __restrict__ idx,
    float* __restrict__ outf, __hip_bfloat16* __restrict__ outb) {
  __shared__ __align__(16) char smem[320 * 66 * 2];  // 42240 B, overlaid stage/Ys
  __hip_bfloat16* Al = (__hip_bfloat16*)smem;              // 320*40
  __hip_bfloat16* Bl = (__hip_bfloat16*)(smem + 25600);    // 64*40
  __hip_bfloat16* Ys = (__hip_bfloat16*)smem;              // 320*66 (post-loop)
  const int tid = threadIdx.x, lane = tid & 63, wv = tid >> 6;
  const int blk = blockIdx.x, n0 = blockIdx.y * 64;
  const int arow = tid >> 2, akc = (tid & 3) * 8;
  const int fm = lane & 15, fq = lane >> 4;
  const __hip_bfloat16* ap[5];
#pragma unroll
  for (int l = 0; l < 5; ++l) {
    int row = arow + l * 64;
    int e = blk * 320 + row;
    int p = e / 20;
    int j = idx[(size_t)p * 20 + (e - p * 20)];
    int src = ((p >> 12) << 12) + j;
    ap[l] = F + (size_t)src * ldf + coff + akc;
  }
  f32x4 acc[5][4];
#pragma unroll
  for (int l = 0; l < 5; ++l)
#pragma unroll
    for (int nt = 0; nt < 4; ++nt) acc[l][nt] = (f32x4){0.f, 0.f, 0.f, 0.f};
  for (int c0 = 0; c0 < K; c0 += 32) {
#pragma unroll
    for (int l = 0; l < 5; ++l)
      *(float4*)&Al[(arow + l * 64) * 40 + akc] = *(const float4*)(ap[l] + c0);
    *(float4*)&Bl[arow * 40 + akc] = *(const float4*)(Wl + (size_t)(n0 + arow) * K + c0 + akc);
    __syncthreads();
    bf16x8 af[5], bfr[4];
#pragma unroll
    for (int l = 0; l < 5; ++l)
      af[l] = *(const bf16x8*)&Al[(wv * 80 + l * 16 + fm) * 40 + fq * 8];
#pragma unroll
    for (int nt = 0; nt < 4; ++nt)
      bfr[nt] = *(const bf16x8*)&Bl[(nt * 16 + fm) * 40 + fq * 8];
#pragma unroll
    for (int l = 0; l < 5; ++l)
#pragma unroll
      for (int nt = 0; nt < 4; ++nt)
        acc[l][nt] = __builtin_amdgcn_mfma_f32_16x16x32_bf16(af[l], bfr[nt], acc[l][nt], 0, 0, 0);
    __syncthreads();
  }
#pragma unroll
  for (int l = 0; l < 5; ++l)
#pragma unroll
    for (int nt = 0; nt < 4; ++nt)
#pragma unroll
      for (int r = 0; r < 4; ++r)
        Ys[(wv * 80 + l * 16 + fq * 4 + r) * 66 + nt * 16 + fm] = __float2bfloat16(acc[l][nt][r]);
  __syncthreads();
  const int col = tid & 63;
#pragma unroll
  for (int gi = 0; gi < 4; ++gi) {
    int grp = wv + gi * 4;
    float m = -INFINITY;
#pragma unroll
    for (int k = 0; k < 20; ++k)
      m = fmaxf(m, __bfloat162float(Ys[(grp * 20 + k) * 66 + col]));
    int p = blk * 16 + grp;
    int o = n0 + col;
    float v = lrelu((m + T[(size_t)p * N + o]) * sc[o] + bi[o]);
    outf[(size_t)p * 512 + o] = v;
    outb[(size_t)p * 512 + o] = __float2bfloat16(v);
  }
}

// ---------------- bias2: one wave per (b,o) ----------------
__global__ __launch_bounds__(256) void k_bias2(const unsigned* __restrict__ gk,
                                               const float* __restrict__ Ws1,
                                               float* __restrict__ b2g) {
  const int lane = threadIdx.x & 63;
  const int wid = (blockIdx.x * 256 + threadIdx.x) >> 6;  // 0..1023
  const int b = wid >> 9, o = wid & 511;
  const float* wr = Ws1 + (size_t)o * 1536 + 512;
  const unsigned* g = gk + b * 1024;
  float acc = 0.f;
#pragma unroll
  for (int c = lane; c < 1024; c += 64) acc = fmaf(dekey(g[c]), wr[c], acc);
#pragma unroll
  for (int off = 32; off; off >>= 1) acc += __shfl_xor(acc, off, 64);
  if (lane == 0) b2g[b * 512 + o] = acc;
}

// ---------------- final head: out = H(8192x256) . Ws3^T + bs3 (fp32) ----------------
__global__ __launch_bounds__(256) void k_out(const float* __restrict__ H,
                                             const float* __restrict__ Ws3,
                                             const float* __restrict__ bs3,
                                             float* __restrict__ out) {
  __shared__ float Ws[13][256];
  const int tid = threadIdx.x;
  for (int e = tid; e < 13 * 256; e += 256) Ws[e >> 8][e & 255] = Ws3[e];
  __syncthreads();
  const int rloc = tid >> 4, o = tid & 15;
  const int row = blockIdx.x * 16 + rloc;
  if (o < 13) {
    const float* h = H + (size_t)row * 256;
    float acc = 0.f;
    for (int c = 0; c < 256; ++c) acc = fmaf(h[c], Ws[o][c], acc);
    out[(size_t)row * 13 + o] = acc + bs3[o];
  }
}

extern "C" void kernel_launch(void* const* d_in, const int* in_sizes, int n_in,
                              void* d_out, int out_size, void* d_ws, size_t ws_size,
                              hipStream_t stream) {
  const float* X   = (const float*)d_in[0];
  const float* W1  = (const float*)d_in[1];
  const float* S1  = (const float*)d_in[2];
  const float* B1  = (const float*)d_in[3];
  const float* W2  = (const float*)d_in[4];
  const float* S2  = (const float*)d_in[5];
  const float* B2  = (const float*)d_in[6];
  const float* W3  = (const float*)d_in[7];
  const float* S3  = (const float*)d_in[8];
  const float* B3  = (const float*)d_in[9];
  const float* W4  = (const float*)d_in[10];
  const float* S4  = (const float*)d_in[11];
  const float* B4  = (const float*)d_in[12];
  const float* Wg  = (const float*)d_in[13];
  const float* Sg  = (const float*)d_in[14];
  const float* Bg  = (const float*)d_in[15];
  const float* Ws1 = (const float*)d_in[16];
  const float* Ss1 = (const float*)d_in[17];
  const float* Bs1 = (const float*)d_in[18];
  const float* Ws2 = (const float*)d_in[19];
  const float* Ss2 = (const float*)d_in[20];
  const float* Bs2 = (const float*)d_in[21];
  const float* Ws3 = (const float*)d_in[22];
  const float* Bs3 = (const float*)d_in[23];

  char* ws = (char*)d_ws;
  float*           xxb   = (float*)(ws + 0);            // 32 KB
  int*             idxb  = (int*)(ws + 32768);          // 640 KB
  unsigned*        gk    = (unsigned*)(ws + 688128);    // 8 KB
  float*           b2g   = (float*)(ws + 696320);       // 4 KB
  __hip_bfloat16*  Wgb   = (__hip_bfloat16*)(ws + 1048576);  // 1 MB
  __hip_bfloat16*  Ws1b  = (__hip_bfloat16*)(ws + 2097152);  // 512 KB
  __hip_bfloat16*  Ws2b  = (__hip_bfloat16*)(ws + 2621440);  // 256 KB
  __hip_bfloat16*  Wlb4  = (__hip_bfloat16*)(ws + 2883584);  // 64 KB
  __hip_bfloat16*  Wdb4  = (__hip_bfloat16*)(ws + 2949120);  // 64 KB
  __hip_bfloat16*  xcatb = (__hip_bfloat16*)(ws + 3145728);  // 8 MB
  float*           xcat  = (float*)(ws + 11534336);          // 16 MB
  char*            region = ws + 28311552;                   // dist / Tbuf+h1b
  float*           dist  = (float*)(region);
  float*           Tbuf  = (float*)(region);
  __hip_bfloat16*  h1b   = (__hip_bfloat16*)(region + 8388608);

  // Full-batch dist (64 MB) if workspace allows; else 1024-row chunking (R6).
  const bool big = (ws_size >= (size_t)28311552 + (64u << 20));

  hipMemsetAsync(gk, 0, 2 * 1024 * sizeof(unsigned), stream);

  // weight bf16 packs (L4 + head only; L1-L3 weights stay fp32)
  k_conv<<<dim3(256, 2), dim3(64), 0, stream>>>(W4, 256, 0, 0, 128, Wlb4);
  k_conv<<<dim3(256, 2), dim3(64), 0, stream>>>(W4, 256, 128, 1, 128, Wdb4);
  k_conv<<<dim3(1024, 8), dim3(64), 0, stream>>>(Wg, 512, 0, 0, 512, Wgb);
  k_conv<<<dim3(512, 8), dim3(64), 0, stream>>>(Ws1, 1536, 0, 0, 512, Ws1b);
  k_conv<<<dim3(256, 8), dim3(64), 0, stream>>>(Ws2, 512, 0, 0, 512, Ws2b);

  // kNN for one layer (fills idxb); selection bit-identical in both paths
  auto run_knn = [&](const float* F, int ldf, int C) {
    k_xx<<<dim3(2048), dim3(256), 0, stream>>>(F, ldf, C, xxb);
    if (big) {
      for (int b = 0; b < 2; ++b) {
        k_dist<<<dim3(64, 64), dim3(256), 0, stream>>>(F, ldf, C, xxb, dist, b, 0);
        k_topk<<<dim3(4096), dim3(256), 0, stream>>>(dist, idxb, b, 0);
      }
    } else {
      for (int b = 0; b < 2; ++b)
        for (int c = 0; c < 4; ++c) {
          k_dist<<<dim3(16, 64), dim3(256), 0, stream>>>(F, ldf, C, xxb, dist, b, c * 1024);
          k_topk<<<dim3(1024), dim3(256), 0, stream>>>(dist, idxb, b, c * 1024);
        }
    }
  };

  // ---- Layer 1 (C=3 -> 64, fp32 exact) ----
  run_knn(X, 3, 3);
  k_edge1<<<dim3(2048), dim3(256), 0, stream>>>(X, W1, S1, B1, idxb, xcat, xcatb);

  // ---- Layer 2 (64 -> 64), fp32 (feeds kNN — must stay exact, R9 proved it) ----
  run_knn(xcat, 512, 64);
  k_pwT<<<dim3(128, 1), dim3(256), 0, stream>>>(xcat, 512, 64, W2, 128, 64, Tbuf, 64);
  k_edge<<<dim3(2048, 1), dim3(256), 0, stream>>>(xcat, 512, 64, W2, S2, B2,
      idxb, Tbuf, 64, xcat + 64, xcatb + 64);

  // ---- Layer 3 (64 -> 128), fp32 (feeds kNN) ----
  run_knn(xcat + 64, 512, 64);
  k_pwT<<<dim3(128, 2), dim3(256), 0, stream>>>(xcat + 64, 512, 64, W3, 128, 64, Tbuf, 128);
  k_edge<<<dim3(2048, 2), dim3(256), 0, stream>>>(xcat + 64, 512, 64, W3, S3, B3,
      idxb, Tbuf, 128, xcat + 128, xcatb + 128);

  // ---- Layer 4 (128 -> 256), bf16 MFMA (x4 feeds nothing discrete) ----
  run_knn(xcat + 128, 512, 128);
  k_mm<0><<<dim3(64, 4), dim3(256), 0, stream>>>(xcatb + 128, 512, 128, Wdb4,
      nullptr, nullptr, nullptr, 256, Tbuf, 256, nullptr, 0, nullptr);
  k_edgem<<<dim3(512, 4), dim3(256), 0, stream>>>(xcatb, 512, 128, 128, Wlb4,
      S4, B4, Tbuf, 256, idxb, xcat + 256, xcatb + 256);

  // ---- head (all bf16 MFMA) ----
  k_mm<2><<<dim3(64, 16), dim3(256), 0, stream>>>(xcatb, 512, 512, Wgb,
      Sg, Bg, nullptr, 1024, nullptr, 0, nullptr, 0, gk);
  k_bias2<<<dim3(256), dim3(256), 0, stream>>>(gk, Ws1, b2g);
  k_mm<1><<<dim3(64, 8), dim3(256), 0, stream>>>(xcatb, 512, 512, Ws1b,
      Ss1, Bs1, b2g, 512, nullptr, 0, h1b, 512, nullptr);
  k_mm<1><<<dim3(64, 4), dim3(256), 0, stream>>>(h1b, 512, 512, Ws2b,
      Ss2, Bs2, nullptr, 256, Tbuf, 256, nullptr, 0, nullptr);
  k_out<<<dim3(512), dim3(256), 0, stream>>>(Tbuf, Ws3, Bs3, (float*)d_out);
}

// Round 11
// 1047.602 us; speedup vs baseline: 1.7850x; 1.1157x over previous
//
#include <hip/hip_runtime.h>
#include <hip/hip_bf16.h>

// DGCNN_Seg forward. B=2, N=4096, K=20. fp32 in/out.
// Round 11: (a) k_topk v3 — register-resident extraction (no 35KB LDS spill,
// 2x occupancy); (b) k_dist v2 — 128x64 tile, 8x4/thread. Both bit-identical
// in distances + selection. L1-L3 fp32-exact (R9 proved necessary); L4+head
// bf16 MFMA.

#define DEVI static __device__ __forceinline__
typedef __attribute__((ext_vector_type(8))) short bf16x8;   // 8 bf16 = 4 VGPR
typedef __attribute__((ext_vector_type(4))) float f32x4;    // MFMA acc
typedef unsigned long long ull;

DEVI float lrelu(float y) { return y > 0.f ? y : 0.2f * y; }
DEVI unsigned okey(float f) {
  unsigned u = __float_as_uint(f);
  return (f < 0.f) ? ~u : (u | 0x80000000u);
}
DEVI float dekey(unsigned k) {
  return __uint_as_float((k & 0x80000000u) ? (k & 0x7fffffffu) : ~k);
}

// ---------------- weight fp32 -> bf16 pack ----------------
__global__ __launch_bounds__(64) void k_conv(const float* __restrict__ src, int lds, int off,
                                             int sub, int Kc, __hip_bfloat16* __restrict__ dst) {
  int o = blockIdx.x, c = blockIdx.y * 64 + threadIdx.x;
  float v = src[(size_t)o * lds + off + c];
  if (sub) v -= src[(size_t)o * lds + c];
  dst[(size_t)o * Kc + c] = __float2bfloat16(v);
}

// ---------------- row squared-norms: one wave per row ----------------
__global__ __launch_bounds__(256) void k_xx(const float* __restrict__ F, int ldf, int C,
                                            float* __restrict__ xx) {
  int lane = threadIdx.x & 63;
  int row = blockIdx.x * 4 + (threadIdx.x >> 6);
  const float* f = F + (size_t)row * ldf;
  float s = 0.f;
  for (int c = lane; c < C; c += 64) { float v = f[c]; s += v * v; }
#pragma unroll
  for (int off = 32; off; off >>= 1) s += __shfl_xor(s, off, 64);
  if (lane == 0) xx[row] = s;
}

// ---------------- pairwise distances v2: 128x64 tile, 8x4 per thread ----------------
// fmaf order per element identical to v1 (chunks of 16 ascending, kk ascending)
__global__ __launch_bounds__(256) void k_dist(const float* __restrict__ F, int ldf, int C,
                                              const float* __restrict__ xx,
                                              float* __restrict__ D, int b, int ibase) {
  __shared__ __align__(16) float As[16][132];
  __shared__ __align__(16) float Bs[16][68];
  const int tid = threadIdx.x;
  const int tx = tid & 15, ty = tid >> 4;
  const int i0 = ibase + blockIdx.x * 128, j0 = blockIdx.y * 64;
  const float* Fb = F + (size_t)b * 4096 * ldf;
  const int arow = tid >> 1, q8 = (tid & 1) * 8;   // A stage: 128 rows x 16 cols
  const int brow = tid >> 2, q4 = (tid & 3) * 4;   // B stage: 64 rows x 16 cols
  float acc[8][4] = {};
  for (int c0 = 0; c0 < C; c0 += 16) {
    if (C - c0 >= 16) {
      float4 a0 = *(const float4*)(Fb + (size_t)(i0 + arow) * ldf + c0 + q8);
      float4 a1 = *(const float4*)(Fb + (size_t)(i0 + arow) * ldf + c0 + q8 + 4);
      As[q8 + 0][arow] = a0.x; As[q8 + 1][arow] = a0.y; As[q8 + 2][arow] = a0.z; As[q8 + 3][arow] = a0.w;
      As[q8 + 4][arow] = a1.x; As[q8 + 5][arow] = a1.y; As[q8 + 6][arow] = a1.z; As[q8 + 7][arow] = a1.w;
      float4 w = *(const float4*)(Fb + (size_t)(j0 + brow) * ldf + c0 + q4);
      Bs[q4 + 0][brow] = w.x; Bs[q4 + 1][brow] = w.y; Bs[q4 + 2][brow] = w.z; Bs[q4 + 3][brow] = w.w;
    } else {
#pragma unroll
      for (int e = 0; e < 8; ++e) {
        int c = c0 + q8 + e;
        As[q8 + e][arow] = (c < C) ? Fb[(size_t)(i0 + arow) * ldf + c] : 0.f;
      }
#pragma unroll
      for (int e = 0; e < 4; ++e) {
        int c = c0 + q4 + e;
        Bs[q4 + e][brow] = (c < C) ? Fb[(size_t)(j0 + brow) * ldf + c] : 0.f;
      }
    }
    __syncthreads();
#pragma unroll
    for (int kk = 0; kk < 16; ++kk) {
      const float4 a4l = *(const float4*)&As[kk][ty * 8];
      const float4 a4h = *(const float4*)&As[kk][ty * 8 + 4];
      const float4 b4 = *(const float4*)&Bs[kk][tx * 4];
      const float av[8] = {a4l.x, a4l.y, a4l.z, a4l.w, a4h.x, a4h.y, a4h.z, a4h.w};
      const float bv[4] = {b4.x, b4.y, b4.z, b4.w};
#pragma unroll
      for (int ii = 0; ii < 8; ++ii)
#pragma unroll
        for (int jj = 0; jj < 4; ++jj)
          acc[ii][jj] = fmaf(av[ii], bv[jj], acc[ii][jj]);
    }
    __syncthreads();
  }
  const float* xxb = xx + b * 4096;
#pragma unroll
  for (int ii = 0; ii < 8; ++ii) {
    int i = i0 + ty * 8 + ii;
    float xi = xxb[i];
    float4 o;
    o.x = xi + xxb[j0 + tx * 4 + 0] - 2.f * acc[ii][0];
    o.y = xi + xxb[j0 + tx * 4 + 1] - 2.f * acc[ii][1];
    o.z = xi + xxb[j0 + tx * 4 + 2] - 2.f * acc[ii][2];
    o.w = xi + xxb[j0 + tx * 4 + 3] - 2.f * acc[ii][3];
    *(float4*)&D[(size_t)(i - ibase) * 4096 + j0 + tx * 4] = o;
  }
}

// ---------------- top-20 v3: 1 block (4 waves) per row, register-resident ----------------
// Per lane: 16 keys -> bitonic sort in regs. Extraction: 20 rounds of u64
// wave-min (shfl_xor tree) + register shift-pop. Tiny LDS (cand only) ->
// occupancy VGPR-bound (~8 blocks/CU). Selection order identical.
__global__ __launch_bounds__(256) void k_topk(const float* __restrict__ D,
                                              int* __restrict__ idx, int b, int ibase) {
  __shared__ ull cand[4][20];
  const int tid = threadIdx.x, lane = tid & 63, wv = tid >> 6;
  const int ir_ = blockIdx.x;
  const float* drow = D + (size_t)ir_ * 4096;
  ull arr[16];
  const int base = wv * 1024 + lane;
#pragma unroll
  for (int it = 0; it < 16; ++it) {
    int j = base + it * 64;
    float d = drow[j];
    arr[it] = ((ull)okey(d) << 32) | (unsigned)j;
  }
  // bitonic sort 16, ascending
#pragma unroll
  for (int k = 2; k <= 16; k <<= 1) {
#pragma unroll
    for (int jj = k >> 1; jj > 0; jj >>= 1) {
#pragma unroll
      for (int i = 0; i < 16; ++i) {
        int l = i ^ jj;
        if (l > i) {
          bool up = ((i & k) == 0);
          bool sw = (arr[i] > arr[l]) == up;
          ull a = arr[i], bb = arr[l];
          arr[i] = sw ? bb : a;
          arr[l] = sw ? a : bb;
        }
      }
    }
  }
  // 20 extraction rounds: u64 wave-min + shift-pop (all registers)
  for (int r = 0; r < 20; ++r) {
    ull v = arr[0];
    ull m = v;
#pragma unroll
    for (int off = 32; off; off >>= 1) {
      ull o = __shfl_xor(m, off, 64);
      m = (o < m) ? o : m;
    }
    bool pop = (v == m);
#pragma unroll
    for (int t = 0; t < 15; ++t) arr[t] = pop ? arr[t + 1] : arr[t];
    arr[15] = pop ? ~0ull : arr[15];
    if (lane == 0) cand[wv][r] = m;
  }
  __syncthreads();
  if (tid == 0) {
    int* op = idx + ((size_t)b * 4096 + ibase + ir_) * 20;
    int p0 = 0, p1 = 0, p2 = 0, p3 = 0;
    for (int r = 0; r < 20; ++r) {
      ull v0 = cand[0][p0], v1 = cand[1][p1], v2 = cand[2][p2], v3 = cand[3][p3];
      ull m01 = v0 < v1 ? v0 : v1;
      ull m23 = v2 < v3 ? v2 : v3;
      ull best = m01 < m23 ? m01 : m23;
      if (best == v0) ++p0; else if (best == v1) ++p1;
      else if (best == v2) ++p2; else ++p3;
      op[r] = (int)(best & 0xffffffffull);
      if (p0 > 19) p0 = 19;
      if (p1 > 19) p1 = 19;
      if (p2 > 19) p2 = 19;
      if (p3 > 19) p3 = 19;
    }
  }
}

// ---------------- EdgeConv layer 1 (fp32, Cin=3): one wave per point ----------------
__global__ __launch_bounds__(256) void k_edge1(const float* __restrict__ xf,
                                               const float* __restrict__ W1,
                                               const float* __restrict__ s1,
                                               const float* __restrict__ b1,
                                               const int* __restrict__ idx,
                                               float* __restrict__ xcat,
                                               __hip_bfloat16* __restrict__ xcatb) {
  const int lane = threadIdx.x & 63;
  const int p = blockIdx.x * 4 + (threadIdx.x >> 6);
  const int bb = p >> 12;
  float wl[3], wr[3];
#pragma unroll
  for (int c = 0; c < 3; ++c) {
    wl[c] = W1[lane * 6 + c];
    wr[c] = W1[lane * 6 + 3 + c];
  }
  const float s = s1[lane], bi = b1[lane];
  const float* xc = xf + (size_t)p * 3;
  const float x0 = xc[0], x1 = xc[1], x2 = xc[2];
  const float t = x0 * (wr[0] - wl[0]) + x1 * (wr[1] - wl[1]) + x2 * (wr[2] - wl[2]);
  const int* ir = idx + (size_t)p * 20;
  float best = -INFINITY;
  for (int k = 0; k < 20; ++k) {
    int j = ir[k];
    const float* xn = xf + ((size_t)(bb << 12) + j) * 3;
    float y = t + xn[0] * wl[0] + xn[1] * wl[1] + xn[2] * wl[2];
    y = lrelu(y * s + bi);
    best = fmaxf(best, y);
  }
  xcat[(size_t)p * 512 + lane] = best;
  xcatb[(size_t)p * 512 + lane] = __float2bfloat16(best);
}

// ---------------- fp32 pointwise GEMM, raw store (T for layers 2-3) ----------------
__global__ __launch_bounds__(256) void k_pwT(const float* __restrict__ A, int lda, int K,
                                             const float* __restrict__ W, int ldw, int wsub,
                                             float* __restrict__ out, int ldo) {
  __shared__ __align__(16) float As[16][68];
  __shared__ __align__(16) float Bs[16][68];
  const int tid = threadIdx.x;
  const int tx = tid & 15, ty = tid >> 4;
  const int i0 = blockIdx.x * 64, o0 = blockIdx.y * 64;
  const int row = tid >> 2, q = (tid & 3) * 4;
  float acc[4][4] = {};
  for (int c0 = 0; c0 < K; c0 += 16) {
    float4 a = *(const float4*)(A + (size_t)(i0 + row) * lda + c0 + q);
    As[q + 0][row] = a.x; As[q + 1][row] = a.y; As[q + 2][row] = a.z; As[q + 3][row] = a.w;
    const float* wp = W + (size_t)(o0 + row) * ldw + c0 + q;
#pragma unroll
    for (int e = 0; e < 4; ++e) Bs[q + e][row] = wp[wsub + e] - wp[e];
    __syncthreads();
#pragma unroll
    for (int kk = 0; kk < 16; ++kk) {
      const float4 a4 = *(const float4*)&As[kk][ty * 4];
      const float4 b4 = *(const float4*)&Bs[kk][tx * 4];
      const float av[4] = {a4.x, a4.y, a4.z, a4.w};
      const float bv[4] = {b4.x, b4.y, b4.z, b4.w};
#pragma unroll
      for (int ii = 0; ii < 4; ++ii)
#pragma unroll
        for (int jj = 0; jj < 4; ++jj)
          acc[ii][jj] = fmaf(av[ii], bv[jj], acc[ii][jj]);
    }
    __syncthreads();
  }
#pragma unroll
  for (int ii = 0; ii < 4; ++ii)
#pragma unroll
    for (int jj = 0; jj < 4; ++jj)
      out[(size_t)(i0 + ty * 4 + ii) * ldo + o0 + tx * 4 + jj] = acc[ii][jj];
}

// ---------------- fp32 EdgeConv GEMM (layers 2-3; feeds kNN, stays exact) ----------------
__global__ __launch_bounds__(256) void k_edge(const float* __restrict__ F, int ldf, int Cin,
                                              const float* __restrict__ W,
                                              const float* __restrict__ sc,
                                              const float* __restrict__ bi,
                                              const int* __restrict__ idx,
                                              const float* __restrict__ T, int ldt,
                                              float* __restrict__ out,
                                              __hip_bfloat16* __restrict__ outb) {
  __shared__ float As[16][81];
  __shared__ __align__(16) float Bs[16][68];
  __shared__ float Ys[80][65];
  const int tid = threadIdx.x;
  const int tx = tid & 15, ty = tid >> 4;
  const int r0 = blockIdx.x * 80;
  const int o0 = blockIdx.y * 64;
  const int ldw = 2 * Cin;
  int grow[5], gcol[5];
#pragma unroll
  for (int l = 0; l < 5; ++l) {
    int e = tid + l * 256;
    int rr = e >> 4;
    gcol[l] = e & 15;
    int gr = r0 + rr;
    int p = gr / 20;
    int j = idx[(size_t)p * 20 + (gr % 20)];
    grow[l] = ((p >> 12) << 12) + j;
  }
  float acc[5][4] = {};
  const int wrow = tid >> 2, wq = (tid & 3) * 4;
  for (int c0 = 0; c0 < Cin; c0 += 16) {
#pragma unroll
    for (int l = 0; l < 5; ++l) {
      int e = tid + l * 256;
      As[gcol[l]][e >> 4] = F[(size_t)grow[l] * ldf + c0 + gcol[l]];
    }
    {
      const float* wp = W + (size_t)(o0 + wrow) * ldw + c0 + wq;
#pragma unroll
      for (int e = 0; e < 4; ++e) Bs[wq + e][wrow] = wp[e];
    }
    __syncthreads();
#pragma unroll
    for (int kk = 0; kk < 16; ++kk) {
      float a[5];
#pragma unroll
      for (int l = 0; l < 5; ++l) a[l] = As[kk][ty + l * 16];
      const float4 b4 = *(const float4*)&Bs[kk][tx * 4];
      const float bv[4] = {b4.x, b4.y, b4.z, b4.w};
#pragma unroll
      for (int l = 0; l < 5; ++l)
#pragma unroll
        for (int jj = 0; jj < 4; ++jj)
          acc[l][jj] = fmaf(a[l], bv[jj], acc[l][jj]);
    }
    __syncthreads();
  }
#pragma unroll
  for (int l = 0; l < 5; ++l) {
    int r = ty + l * 16;
    int p = (r0 + r) / 20;
#pragma unroll
    for (int jj = 0; jj < 4; ++jj) {
      int o = o0 + tx * 4 + jj;
      float y = (acc[l][jj] + T[(size_t)p * ldt + o]) * sc[o] + bi[o];
      Ys[r][tx * 4 + jj] = lrelu(y);
    }
  }
  __syncthreads();
  const int grp = tid >> 6, col = tid & 63;
  float m = -INFINITY;
#pragma unroll
  for (int k = 0; k < 20; ++k) m = fmaxf(m, Ys[grp * 20 + k][col]);
  const int p = blockIdx.x * 4 + grp;
  out[(size_t)p * 512 + o0 + col] = m;
  outb[(size_t)p * 512 + o0 + col] = __float2bfloat16(m);
}

// ---------------- MFMA bf16 GEMM: block 128(M)x64(N), 4 waves x (32x64) ----------------
template <int EPI>
__global__ __launch_bounds__(256) void k_mm(
    const __hip_bfloat16* __restrict__ A, int lda, int K,
    const __hip_bfloat16* __restrict__ B,  // [N][K] bf16
    const float* __restrict__ sc, const float* __restrict__ bi,
    const float* __restrict__ extra, int Ncols,
    float* __restrict__ outf, int ldof,
    __hip_bfloat16* __restrict__ outb, int ldob,
    unsigned* __restrict__ gmax) {
  __shared__ __align__(16) __hip_bfloat16 Al[128 * 40];
  __shared__ __align__(16) __hip_bfloat16 Bl[64 * 40];
  __shared__ float Red[4][64];
  const int tid = threadIdx.x, lane = tid & 63, wv = tid >> 6;
  const int m0 = blockIdx.x * 128, n0 = blockIdx.y * 64;
  const int arow = tid >> 2, akc = (tid & 3) * 8;
  const int fm = lane & 15, fq = lane >> 4;
  f32x4 acc[2][4];
#pragma unroll
  for (int mt = 0; mt < 2; ++mt)
#pragma unroll
    for (int nt = 0; nt < 4; ++nt) acc[mt][nt] = (f32x4){0.f, 0.f, 0.f, 0.f};
  for (int c0 = 0; c0 < K; c0 += 32) {
#pragma unroll
    for (int l = 0; l < 2; ++l) {
      int r = arow + l * 64;
      *(float4*)&Al[r * 40 + akc] = *(const float4*)(A + (size_t)(m0 + r) * lda + c0 + akc);
    }
    *(float4*)&Bl[arow * 40 + akc] = *(const float4*)(B + (size_t)(n0 + arow) * K + c0 + akc);
    __syncthreads();
    bf16x8 af[2], bfr[4];
#pragma unroll
    for (int mt = 0; mt < 2; ++mt)
      af[mt] = *(const bf16x8*)&Al[(wv * 32 + mt * 16 + fm) * 40 + fq * 8];
#pragma unroll
    for (int nt = 0; nt < 4; ++nt)
      bfr[nt] = *(const bf16x8*)&Bl[(nt * 16 + fm) * 40 + fq * 8];
#pragma unroll
    for (int mt = 0; mt < 2; ++mt)
#pragma unroll
      for (int nt = 0; nt < 4; ++nt)
        acc[mt][nt] = __builtin_amdgcn_mfma_f32_16x16x32_bf16(af[mt], bfr[nt], acc[mt][nt], 0, 0, 0);
    __syncthreads();
  }
  const int bidx = m0 >> 12;
  if (EPI == 0) {
#pragma unroll
    for (int mt = 0; mt < 2; ++mt)
#pragma unroll
      for (int nt = 0; nt < 4; ++nt)
#pragma unroll
        for (int r = 0; r < 4; ++r)
          outf[(size_t)(m0 + wv * 32 + mt * 16 + fq * 4 + r) * ldof + n0 + nt * 16 + fm] =
              acc[mt][nt][r];
  } else if (EPI == 1) {
#pragma unroll
    for (int nt = 0; nt < 4; ++nt) {
      int col = n0 + nt * 16 + fm;
      float s = sc[col], bb = bi[col];
      float ex = extra ? extra[bidx * Ncols + col] : 0.f;
#pragma unroll
      for (int mt = 0; mt < 2; ++mt)
#pragma unroll
        for (int r = 0; r < 4; ++r) {
          float v = lrelu((acc[mt][nt][r] + ex) * s + bb);
          size_t rr = (size_t)(m0 + wv * 32 + mt * 16 + fq * 4 + r);
          if (outf) outf[rr * ldof + col] = v;
          if (outb) outb[rr * ldob + col] = __float2bfloat16(v);
        }
    }
  } else {
#pragma unroll
    for (int nt = 0; nt < 4; ++nt) {
      int col = n0 + nt * 16 + fm;
      float s = sc[col], bb = bi[col];
      float m = -INFINITY;
#pragma unroll
      for (int mt = 0; mt < 2; ++mt)
#pragma unroll
        for (int r = 0; r < 4; ++r) m = fmaxf(m, lrelu(acc[mt][nt][r] * s + bb));
      m = fmaxf(m, __shfl_xor(m, 16, 64));
      m = fmaxf(m, __shfl_xor(m, 32, 64));
      if (fq == 0) Red[wv][nt * 16 + fm] = m;
    }
    __syncthreads();
    if (tid < 64) {
      float m = fmaxf(fmaxf(Red[0][tid], Red[1][tid]), fmaxf(Red[2][tid], Red[3][tid]));
      atomicMax(&gmax[bidx * Ncols + n0 + tid], okey(m));
    }
  }
}

// ---------------- MFMA bf16 EdgeConv (layer 4): 320 edges x 64 cols / block ----------------
__global__ __launch_bounds__(256) void k_edgem(
    const __hip_bfloat16* __restrict__ F, int ldf, int coff, int K,
    const __hip_bfloat16* __restrict__ Wl,  // [N][K] bf16
    const float* __restrict__ sc, const float* __restrict__ bi,
    const float* __restrict__ T, int N,
    const int* __restrict__ idx,
    float* __restrict__ outf, __hip_bfloat16* __restrict__ outb) {
  __shared__ __align__(16) char smem[320 * 66 * 2];  // 42240 B, overlaid stage/Ys
  __hip_bfloat16* Al = (__hip_bfloat16*)smem;              // 320*40
  __hip_bfloat16* Bl = (__hip_bfloat16*)(smem + 25600);    // 64*40
  __hip_bfloat16* Ys = (__hip_bfloat16*)smem;              // 320*66 (post-loop)
  const int tid = threadIdx.x, lane = tid & 63, wv = tid >> 6;
  const int blk = blockIdx.x, n0 = blockIdx.y * 64;
  const int arow = tid >> 2, akc = (tid & 3) * 8;
  const int fm = lane & 15, fq = lane >> 4;
  const __hip_bfloat16* ap[5];
#pragma unroll
  for (int l = 0; l < 5; ++l) {
    int row = arow + l * 64;
    int e = blk * 320 + row;
    int p = e / 20;
    int j = idx[(size_t)p * 20 + (e - p * 20)];
    int src = ((p >> 12) << 12) + j;
    ap[l] = F + (size_t)src * ldf + coff + akc;
  }
  f32x4 acc[5][4];
#pragma unroll
  for (int l = 0; l < 5; ++l)
#pragma unroll
    for (int nt = 0; nt < 4; ++nt) acc[l][nt] = (f32x4){0.f, 0.f, 0.f, 0.f};
  for (int c0 = 0; c0 < K; c0 += 32) {
#pragma unroll
    for (int l = 0; l < 5; ++l)
      *(float4*)&Al[(arow + l * 64) * 40 + akc] = *(const float4*)(ap[l] + c0);
    *(float4*)&Bl[arow * 40 + akc] = *(const float4*)(Wl + (size_t)(n0 + arow) * K + c0 + akc);
    __syncthreads();
    bf16x8 af[5], bfr[4];
#pragma unroll
    for (int l = 0; l < 5; ++l)
      af[l] = *(const bf16x8*)&Al[(wv * 80 + l * 16 + fm) * 40 + fq * 8];
#pragma unroll
    for (int nt = 0; nt < 4; ++nt)
      bfr[nt] = *(const bf16x8*)&Bl[(nt * 16 + fm) * 40 + fq * 8];
#pragma unroll
    for (int l = 0; l < 5; ++l)
#pragma unroll
      for (int nt = 0; nt < 4; ++nt)
        acc[l][nt] = __builtin_amdgcn_mfma_f32_16x16x32_bf16(af[l], bfr[nt], acc[l][nt], 0, 0, 0);
    __syncthreads();
  }
#pragma unroll
  for (int l = 0; l < 5; ++l)
#pragma unroll
    for (int nt = 0; nt < 4; ++nt)
#pragma unroll
      for (int r = 0; r < 4; ++r)
        Ys[(wv * 80 + l * 16 + fq * 4 + r) * 66 + nt * 16 + fm] = __float2bfloat16(acc[l][nt][r]);
  __syncthreads();
  const int col = tid & 63;
#pragma unroll
  for (int gi = 0; gi < 4; ++gi) {
    int grp = wv + gi * 4;
    float m = -INFINITY;
#pragma unroll
    for (int k = 0; k < 20; ++k)
      m = fmaxf(m, __bfloat162float(Ys[(grp * 20 + k) * 66 + col]));
    int p = blk * 16 + grp;
    int o = n0 + col;
    float v = lrelu((m + T[(size_t)p * N + o]) * sc[o] + bi[o]);
    outf[(size_t)p * 512 + o] = v;
    outb[(size_t)p * 512 + o] = __float2bfloat16(v);
  }
}

// ---------------- bias2: one wave per (b,o) ----------------
__global__ __launch_bounds__(256) void k_bias2(const unsigned* __restrict__ gk,
                                               const float* __restrict__ Ws1,
                                               float* __restrict__ b2g) {
  const int lane = threadIdx.x & 63;
  const int wid = (blockIdx.x * 256 + threadIdx.x) >> 6;  // 0..1023
  const int b = wid >> 9, o = wid & 511;
  const float* wr = Ws1 + (size_t)o * 1536 + 512;
  const unsigned* g = gk + b * 1024;
  float acc = 0.f;
#pragma unroll
  for (int c = lane; c < 1024; c += 64) acc = fmaf(dekey(g[c]), wr[c], acc);
#pragma unroll
  for (int off = 32; off; off >>= 1) acc += __shfl_xor(acc, off, 64);
  if (lane == 0) b2g[b * 512 + o] = acc;
}

// ---------------- final head: out = H(8192x256) . Ws3^T + bs3 (fp32) ----------------
__global__ __launch_bounds__(256) void k_out(const float* __restrict__ H,
                                             const float* __restrict__ Ws3,
                                             const float* __restrict__ bs3,
                                             float* __restrict__ out) {
  __shared__ float Ws[13][256];
  const int tid = threadIdx.x;
  for (int e = tid; e < 13 * 256; e += 256) Ws[e >> 8][e & 255] = Ws3[e];
  __syncthreads();
  const int rloc = tid >> 4, o = tid & 15;
  const int row = blockIdx.x * 16 + rloc;
  if (o < 13) {
    const float* h = H + (size_t)row * 256;
    float acc = 0.f;
    for (int c = 0; c < 256; ++c) acc = fmaf(h[c], Ws[o][c], acc);
    out[(size_t)row * 13 + o] = acc + bs3[o];
  }
}

extern "C" void kernel_launch(void* const* d_in, const int* in_sizes, int n_in,
                              void* d_out, int out_size, void* d_ws, size_t ws_size,
                              hipStream_t stream) {
  const float* X   = (const float*)d_in[0];
  const float* W1  = (const float*)d_in[1];
  const float* S1  = (const float*)d_in[2];
  const float* B1  = (const float*)d_in[3];
  const float* W2  = (const float*)d_in[4];
  const float* S2  = (const float*)d_in[5];
  const float* B2  = (const float*)d_in[6];
  const float* W3  = (const float*)d_in[7];
  const float* S3  = (const float*)d_in[8];
  const float* B3  = (const float*)d_in[9];
  const float* W4  = (const float*)d_in[10];
  const float* S4  = (const float*)d_in[11];
  const float* B4  = (const float*)d_in[12];
  const float* Wg  = (const float*)d_in[13];
  const float* Sg  = (const float*)d_in[14];
  const float* Bg  = (const float*)d_in[15];
  const float* Ws1 = (const float*)d_in[16];
  const float* Ss1 = (const float*)d_in[17];
  const float* Bs1 = (const float*)d_in[18];
  const float* Ws2 = (const float*)d_in[19];
  const float* Ss2 = (const float*)d_in[20];
  const float* Bs2 = (const float*)d_in[21];
  const float* Ws3 = (const float*)d_in[22];
  const float* Bs3 = (const float*)d_in[23];

  char* ws = (char*)d_ws;
  float*           xxb   = (float*)(ws + 0);            // 32 KB
  int*             idxb  = (int*)(ws + 32768);          // 640 KB
  unsigned*        gk    = (unsigned*)(ws + 688128);    // 8 KB
  float*           b2g   = (float*)(ws + 696320);       // 4 KB
  __hip_bfloat16*  Wgb   = (__hip_bfloat16*)(ws + 1048576);  // 1 MB
  __hip_bfloat16*  Ws1b  = (__hip_bfloat16*)(ws + 2097152);  // 512 KB
  __hip_bfloat16*  Ws2b  = (__hip_bfloat16*)(ws + 2621440);  // 256 KB
  __hip_bfloat16*  Wlb4  = (__hip_bfloat16*)(ws + 2883584);  // 64 KB
  __hip_bfloat16*  Wdb4  = (__hip_bfloat16*)(ws + 2949120);  // 64 KB
  __hip_bfloat16*  xcatb = (__hip_bfloat16*)(ws + 3145728);  // 8 MB
  float*           xcat  = (float*)(ws + 11534336);          // 16 MB
  char*            region = ws + 28311552;                   // dist / Tbuf+h1b
  float*           dist  = (float*)(region);
  float*           Tbuf  = (float*)(region);
  __hip_bfloat16*  h1b   = (__hip_bfloat16*)(region + 8388608);

  // Full-batch dist (64 MB) if workspace allows; else 1024-row chunking.
  const bool big = (ws_size >= (size_t)28311552 + (64u << 20));

  hipMemsetAsync(gk, 0, 2 * 1024 * sizeof(unsigned), stream);

  // weight bf16 packs (L4 + head only; L1-L3 weights stay fp32)
  k_conv<<<dim3(256, 2), dim3(64), 0, stream>>>(W4, 256, 0, 0, 128, Wlb4);
  k_conv<<<dim3(256, 2), dim3(64), 0, stream>>>(W4, 256, 128, 1, 128, Wdb4);
  k_conv<<<dim3(1024, 8), dim3(64), 0, stream>>>(Wg, 512, 0, 0, 512, Wgb);
  k_conv<<<dim3(512, 8), dim3(64), 0, stream>>>(Ws1, 1536, 0, 0, 512, Ws1b);
  k_conv<<<dim3(256, 8), dim3(64), 0, stream>>>(Ws2, 512, 0, 0, 512, Ws2b);

  // kNN for one layer (fills idxb); selection bit-identical in both paths
  auto run_knn = [&](const float* F, int ldf, int C) {
    k_xx<<<dim3(2048), dim3(256), 0, stream>>>(F, ldf, C, xxb);
    if (big) {
      for (int b = 0; b < 2; ++b) {
        k_dist<<<dim3(32, 64), dim3(256), 0, stream>>>(F, ldf, C, xxb, dist, b, 0);
        k_topk<<<dim3(4096), dim3(256), 0, stream>>>(dist, idxb, b, 0);
      }
    } else {
      for (int b = 0; b < 2; ++b)
        for (int c = 0; c < 4; ++c) {
          k_dist<<<dim3(8, 64), dim3(256), 0, stream>>>(F, ldf, C, xxb, dist, b, c * 1024);
          k_topk<<<dim3(1024), dim3(256), 0, stream>>>(dist, idxb, b, c * 1024);
        }
    }
  };

  // ---- Layer 1 (C=3 -> 64, fp32 exact) ----
  run_knn(X, 3, 3);
  k_edge1<<<dim3(2048), dim3(256), 0, stream>>>(X, W1, S1, B1, idxb, xcat, xcatb);

  // ---- Layer 2 (64 -> 64), fp32 (feeds kNN — must stay exact, R9 proved it) ----
  run_knn(xcat, 512, 64);
  k_pwT<<<dim3(128, 1), dim3(256), 0, stream>>>(xcat, 512, 64, W2, 128, 64, Tbuf, 64);
  k_edge<<<dim3(2048, 1), dim3(256), 0, stream>>>(xcat, 512, 64, W2, S2, B2,
      idxb, Tbuf, 64, xcat + 64, xcatb + 64);

  // ---- Layer 3 (64 -> 128), fp32 (feeds kNN) ----
  run_knn(xcat + 64, 512, 64);
  k_pwT<<<dim3(128, 2), dim3(256), 0, stream>>>(xcat + 64, 512, 64, W3, 128, 64, Tbuf, 128);
  k_edge<<<dim3(2048, 2), dim3(256), 0, stream>>>(xcat + 64, 512, 64, W3, S3, B3,
      idxb, Tbuf, 128, xcat + 128, xcatb + 128);

  // ---- Layer 4 (128 -> 256), bf16 MFMA (x4 feeds nothing discrete) ----
  run_knn(xcat + 128, 512, 128);
  k_mm<0><<<dim3(64, 4), dim3(256), 0, stream>>>(xcatb + 128, 512, 128, Wdb4,
      nullptr, nullptr, nullptr, 256, Tbuf, 256, nullptr, 0, nullptr);
  k_edgem<<<dim3(512, 4), dim3(256), 0, stream>>>(xcatb, 512, 128, 128, Wlb4,
      S4, B4, Tbuf, 256, idxb, xcat + 256, xcatb + 256);

  // ---- head (all bf16 MFMA) ----
  k_mm<2><<<dim3(64, 16), dim3(256), 0, stream>>>(xcatb, 512, 512, Wgb,
      Sg, Bg, nullptr, 1024, nullptr, 0, nullptr, 0, gk);
  k_bias2<<<dim3(256), dim3(256), 0, stream>>>(gk, Ws1, b2g);
  k_mm<1><<<dim3(64, 8), dim3(256), 0, stream>>>(xcatb, 512, 512, Ws1b,
      Ss1, Bs1, b2g, 512, nullptr, 0, h1b, 512, nullptr);
  k_mm<1><<<dim3(64, 4), dim3(256), 0, stream>>>(h1b, 512, 512, Ws2b,
      Ss2, Bs2, nullptr, 256, Tbuf, 256, nullptr, 0, nullptr);
  k_out<<<dim3(512), dim3(256), 0, stream>>>(Tbuf, Ws3, Bs3, (float*)d_out);
}